// Round 1
// baseline (1481.495 us; speedup 1.0000x reference)
//
#include <hip/hip_runtime.h>
#include <math.h>

// Shapes (fixed by the reference)
constexpr int Bc = 4, Tc = 1024, Ec = 1024, Hc = 16, Fc = 64;
constexpr int Mc = Bc * Tc; // 4096

// ---------------------------------------------------------------------------
// GEMM: QKV projection. C[m,n] = sum_e x[m,e] * w[h,e,f] (n = h*64+f).
// Output layout [B,H,T,F] for attention convenience.
// Tile 64x64, BK=16, 256 threads, 4x4 per thread.
// ---------------------------------------------------------------------------
__global__ __launch_bounds__(256) void gemm_proj(
    const float* __restrict__ x, const float* __restrict__ qw,
    const float* __restrict__ kw, const float* __restrict__ vw,
    float* __restrict__ qo, float* __restrict__ ko, float* __restrict__ vo)
{
  const float* w = (blockIdx.z == 0) ? qw : (blockIdx.z == 1) ? kw : vw;
  float* op      = (blockIdx.z == 0) ? qo : (blockIdx.z == 1) ? ko : vo;
  const int m0 = blockIdx.x * 64, n0 = blockIdx.y * 64;
  const int h = n0 >> 6; // n-tile == one head (F=64)
  __shared__ float As[16][64], Bs[16][64];
  const int tid = threadIdx.x;
  const int tx = tid & 15, ty = tid >> 4;
  const int arow = tid >> 2, ac4 = tid & 3;
  const int brow = tid >> 4, bc4 = tid & 15;
  float acc[4][4] = {};
  const float* ag = x + (size_t)(m0 + arow) * Ec + ac4 * 4;
  const float* bg = w + (size_t)h * Ec * Fc + (size_t)brow * Fc + bc4 * 4;
  for (int k0 = 0; k0 < Ec; k0 += 16) {
    float4 a = *(const float4*)(ag + k0);
    float4 b = *(const float4*)(bg + (size_t)k0 * Fc);
    __syncthreads();
    As[ac4 * 4 + 0][arow] = a.x; As[ac4 * 4 + 1][arow] = a.y;
    As[ac4 * 4 + 2][arow] = a.z; As[ac4 * 4 + 3][arow] = a.w;
    *(float4*)&Bs[brow][bc4 * 4] = b;
    __syncthreads();
#pragma unroll
    for (int kk = 0; kk < 16; ++kk) {
      float4 av = *(const float4*)&As[kk][ty * 4];
      float4 bv = *(const float4*)&Bs[kk][tx * 4];
      float aa[4] = {av.x, av.y, av.z, av.w};
      float bb[4] = {bv.x, bv.y, bv.z, bv.w};
#pragma unroll
      for (int i = 0; i < 4; ++i)
#pragma unroll
        for (int j = 0; j < 4; ++j) acc[i][j] += aa[i] * bb[j];
    }
  }
#pragma unroll
  for (int i = 0; i < 4; ++i) {
    int m = m0 + ty * 4 + i;
    int b = m >> 10, t = m & 1023;
    float4 o = make_float4(acc[i][0], acc[i][1], acc[i][2], acc[i][3]);
    *(float4*)&op[(size_t)(((b * Hc + h) * Tc + t)) * Fc + tx * 4] = o;
  }
}

// ---------------------------------------------------------------------------
// Attention: one thread = one query row. Faithful multiplicative mask:
// masked factor = fp32(-1e9 + 1) == -1e9f exactly. Online softmax.
// Block: 256 threads = 256 q rows of one (b,h). K/V tiles (64x64) in LDS.
// ---------------------------------------------------------------------------
__global__ __launch_bounds__(256) void attn(
    const float* __restrict__ q, const float* __restrict__ k,
    const float* __restrict__ v, float* __restrict__ z)
{
  const int bh = blockIdx.x >> 2;
  const int row = (blockIdx.x & 3) * 256 + threadIdx.x;
  const float* qp = q + ((size_t)bh * Tc + row) * Fc;
  float4 qv[16];
#pragma unroll
  for (int i = 0; i < 16; ++i) qv[i] = ((const float4*)qp)[i];
  __shared__ float Ks[64][64], Vs[64][64];
  float4 acc[16];
#pragma unroll
  for (int i = 0; i < 16; ++i) acc[i] = make_float4(0.f, 0.f, 0.f, 0.f);
  float m = -INFINITY, l = 0.f;
  const float* kb = k + (size_t)bh * Tc * Fc;
  const float* vb = v + (size_t)bh * Tc * Fc;
  const float MASKF = -1.0e9f + 1.0f; // folds to -1e9f in fp32, matching jax
  for (int kt = 0; kt < Tc; kt += 64) {
    __syncthreads();
#pragma unroll
    for (int u = 0; u < 4; ++u) {
      int idx = u * 256 + threadIdx.x;
      int r = idx >> 4, c4 = idx & 15;
      *(float4*)&Ks[r][c4 * 4] = *(const float4*)&kb[(size_t)(kt + r) * Fc + c4 * 4];
      *(float4*)&Vs[r][c4 * 4] = *(const float4*)&vb[(size_t)(kt + r) * Fc + c4 * 4];
    }
    __syncthreads();
    for (int kk = 0; kk < 64; ++kk) {
      const float4* kr = (const float4*)&Ks[kk][0];
      float s = 0.f;
#pragma unroll
      for (int i = 0; i < 16; ++i) {
        float4 kv = kr[i];
        s += qv[i].x * kv.x + qv[i].y * kv.y + qv[i].z * kv.z + qv[i].w * kv.w;
      }
      if (kt + kk > row) s *= MASKF;  // multiplicative mask, faithful to ref
      s *= 0.125f;                    // 1/sqrt(F)
      const float4* vr = (const float4*)&Vs[kk][0];
      if (s > m) {
        float corr = __expf(m - s);   // exp(-inf)=0 on first hit
        m = s;
        l = l * corr + 1.f;
#pragma unroll
        for (int i = 0; i < 16; ++i) {
          float4 vv = vr[i];
          acc[i].x = acc[i].x * corr + vv.x;
          acc[i].y = acc[i].y * corr + vv.y;
          acc[i].z = acc[i].z * corr + vv.z;
          acc[i].w = acc[i].w * corr + vv.w;
        }
      } else {
        float p = __expf(s - m);
        l += p;
#pragma unroll
        for (int i = 0; i < 16; ++i) {
          float4 vv = vr[i];
          acc[i].x += p * vv.x; acc[i].y += p * vv.y;
          acc[i].z += p * vv.z; acc[i].w += p * vv.w;
        }
      }
    }
  }
  const float inv = 1.f / l;
  const int b = bh >> 4, h = bh & 15;
  float* zp = z + ((size_t)(b * Tc + row)) * Ec + h * Fc; // merged-head [B,T,E]
#pragma unroll
  for (int i = 0; i < 16; ++i) {
    ((float4*)zp)[i] = make_float4(acc[i].x * inv, acc[i].y * inv,
                                   acc[i].z * inv, acc[i].w * inv);
  }
}

// ---------------------------------------------------------------------------
// GEMM: per-batch feature reduction. s1[b,t,d] = x[b,t,d] + sum_e z[b,t,e]*frw[b,e,d]
// Also emits per-block (sum, sumsq) partials for LN1.
// ---------------------------------------------------------------------------
__global__ __launch_bounds__(256) void gemm_fr(
    const float* __restrict__ z, const float* __restrict__ frw,
    const float* __restrict__ x, float* __restrict__ s1,
    float2* __restrict__ part)
{
  const int bb = blockIdx.z;
  const int m0 = blockIdx.x * 64, n0 = blockIdx.y * 64;
  __shared__ float As[16][64], Bs[16][64];
  __shared__ float2 red[256];
  const int tid = threadIdx.x;
  const int tx = tid & 15, ty = tid >> 4;
  const int arow = tid >> 2, ac4 = tid & 3;
  const int brow = tid >> 4, bc4 = tid & 15;
  float acc[4][4] = {};
  const float* ag = z + (size_t)(bb * Tc + m0 + arow) * Ec + ac4 * 4;
  const float* bg = frw + (size_t)bb * Ec * Ec + (size_t)brow * Ec + n0 + bc4 * 4;
  for (int k0 = 0; k0 < Ec; k0 += 16) {
    float4 a = *(const float4*)(ag + k0);
    float4 b = *(const float4*)(bg + (size_t)k0 * Ec);
    __syncthreads();
    As[ac4 * 4 + 0][arow] = a.x; As[ac4 * 4 + 1][arow] = a.y;
    As[ac4 * 4 + 2][arow] = a.z; As[ac4 * 4 + 3][arow] = a.w;
    *(float4*)&Bs[brow][bc4 * 4] = b;
    __syncthreads();
#pragma unroll
    for (int kk = 0; kk < 16; ++kk) {
      float4 av = *(const float4*)&As[kk][ty * 4];
      float4 bv = *(const float4*)&Bs[kk][tx * 4];
      float aa[4] = {av.x, av.y, av.z, av.w};
      float bb2[4] = {bv.x, bv.y, bv.z, bv.w};
#pragma unroll
      for (int i = 0; i < 4; ++i)
#pragma unroll
        for (int j = 0; j < 4; ++j) acc[i][j] += aa[i] * bb2[j];
    }
  }
  float sum = 0.f, sq = 0.f;
#pragma unroll
  for (int i = 0; i < 4; ++i) {
    int m = m0 + ty * 4 + i;
    size_t base = (size_t)(bb * Tc + m) * Ec + n0 + tx * 4;
    float4 xv = *(const float4*)&x[base];
    float4 o = make_float4(xv.x + acc[i][0], xv.y + acc[i][1],
                           xv.z + acc[i][2], xv.w + acc[i][3]);
    *(float4*)&s1[base] = o;
    sum += o.x + o.y + o.z + o.w;
    sq  += o.x * o.x + o.y * o.y + o.z * o.z + o.w * o.w;
  }
  red[tid] = make_float2(sum, sq);
  __syncthreads();
  for (int s = 128; s > 0; s >>= 1) {
    if (tid < s) { red[tid].x += red[tid + s].x; red[tid].y += red[tid + s].y; }
    __syncthreads();
  }
  if (tid == 0) part[(bb * 16 + blockIdx.x) * 16 + blockIdx.y] = red[0];
}

// ---------------------------------------------------------------------------
// GEMM: feed-forward. s2[m,d] = z1[m,d] + relu(sum_e z1[m,e]*ffw[d,e] + ffb[d])
// B operand is ffw transposed (staged with transpose). LN2 partials emitted.
// ---------------------------------------------------------------------------
__global__ __launch_bounds__(256) void gemm_ff(
    const float* __restrict__ z1, const float* __restrict__ ffw,
    const float* __restrict__ ffb, float* __restrict__ s2,
    float2* __restrict__ part)
{
  const int m0 = blockIdx.x * 64, n0 = blockIdx.y * 64;
  __shared__ float As[16][64], Bs[16][64];
  __shared__ float2 red[256];
  const int tid = threadIdx.x;
  const int tx = tid & 15, ty = tid >> 4;
  const int arow = tid >> 2, ac4 = tid & 3;
  float acc[4][4] = {};
  const float* ag = z1 + (size_t)(m0 + arow) * Ec + ac4 * 4;
  const float* bg = ffw + (size_t)(n0 + arow) * Ec + ac4 * 4;
  for (int k0 = 0; k0 < Ec; k0 += 16) {
    float4 a = *(const float4*)(ag + k0);
    float4 b = *(const float4*)(bg + k0);
    __syncthreads();
    As[ac4 * 4 + 0][arow] = a.x; As[ac4 * 4 + 1][arow] = a.y;
    As[ac4 * 4 + 2][arow] = a.z; As[ac4 * 4 + 3][arow] = a.w;
    Bs[ac4 * 4 + 0][arow] = b.x; Bs[ac4 * 4 + 1][arow] = b.y;
    Bs[ac4 * 4 + 2][arow] = b.z; Bs[ac4 * 4 + 3][arow] = b.w;
    __syncthreads();
#pragma unroll
    for (int kk = 0; kk < 16; ++kk) {
      float4 av = *(const float4*)&As[kk][ty * 4];
      float4 bv = *(const float4*)&Bs[kk][tx * 4];
      float aa[4] = {av.x, av.y, av.z, av.w};
      float bb2[4] = {bv.x, bv.y, bv.z, bv.w};
#pragma unroll
      for (int i = 0; i < 4; ++i)
#pragma unroll
        for (int j = 0; j < 4; ++j) acc[i][j] += aa[i] * bb2[j];
    }
  }
  float4 bias = *(const float4*)&ffb[n0 + tx * 4];
  float sum = 0.f, sq = 0.f;
#pragma unroll
  for (int i = 0; i < 4; ++i) {
    int m = m0 + ty * 4 + i;
    size_t base = (size_t)m * Ec + n0 + tx * 4;
    float4 zv = *(const float4*)&z1[base];
    float4 o;
    o.x = zv.x + fmaxf(acc[i][0] + bias.x, 0.f);
    o.y = zv.y + fmaxf(acc[i][1] + bias.y, 0.f);
    o.z = zv.z + fmaxf(acc[i][2] + bias.z, 0.f);
    o.w = zv.w + fmaxf(acc[i][3] + bias.w, 0.f);
    *(float4*)&s2[base] = o;
    sum += o.x + o.y + o.z + o.w;
    sq  += o.x * o.x + o.y * o.y + o.z * o.z + o.w * o.w;
  }
  red[tid] = make_float2(sum, sq);
  __syncthreads();
  for (int s = 128; s > 0; s >>= 1) {
    if (tid < s) { red[tid].x += red[tid + s].x; red[tid].y += red[tid + s].y; }
    __syncthreads();
  }
  if (tid == 0) part[blockIdx.x * 16 + blockIdx.y] = red[0];
}

// ---------------------------------------------------------------------------
// LN stats: one block per batch; deterministic fp64 reduce of 256 partials.
// stats[b] = (mean, rstd) over the batch's [T,E] slab (1,048,576 elements).
// ---------------------------------------------------------------------------
__global__ __launch_bounds__(256) void ln_stats(
    const float2* __restrict__ part, float2* __restrict__ stats)
{
  __shared__ double sd[256], sq[256];
  const int tid = threadIdx.x;
  float2 p = part[blockIdx.x * 256 + tid];
  sd[tid] = (double)p.x; sq[tid] = (double)p.y;
  __syncthreads();
  for (int s = 128; s > 0; s >>= 1) {
    if (tid < s) { sd[tid] += sd[tid + s]; sq[tid] += sq[tid + s]; }
    __syncthreads();
  }
  if (tid == 0) {
    const double n = (double)Tc * Ec;
    double mean = sd[0] / n;
    double var = sq[0] / n - mean * mean;
    double rs = 1.0 / sqrt(var + 1e-5);
    stats[blockIdx.x] = make_float2((float)mean, (float)rs);
  }
}

// ---------------------------------------------------------------------------
// LN normalize: out = (s - mean)*rstd*w[t,e] + b[t,e]; float4 elementwise.
// ---------------------------------------------------------------------------
__global__ __launch_bounds__(256) void ln_norm(
    const float* __restrict__ s, const float2* __restrict__ stats,
    const float* __restrict__ w, const float* __restrict__ bias,
    float* __restrict__ out)
{
  int i = blockIdx.x * 256 + threadIdx.x;
  if (i >= (Bc * Tc * Ec) / 4) return;
  int b = i >> 18;                 // T*E/4 = 262144 = 2^18
  int te4 = i & ((1 << 18) - 1);
  float2 st = stats[b];
  float4 sv = ((const float4*)s)[i];
  float4 wv = ((const float4*)w)[te4];
  float4 bv = ((const float4*)bias)[te4];
  float4 o;
  o.x = (sv.x - st.x) * st.y * wv.x + bv.x;
  o.y = (sv.y - st.x) * st.y * wv.y + bv.y;
  o.z = (sv.z - st.x) * st.y * wv.z + bv.z;
  o.w = (sv.w - st.x) * st.y * wv.w + bv.w;
  ((float4*)out)[i] = o;
}

// ---------------------------------------------------------------------------
extern "C" void kernel_launch(void* const* d_in, const int* in_sizes, int n_in,
                              void* d_out, int out_size, void* d_ws, size_t ws_size,
                              hipStream_t stream)
{
  const float* x    = (const float*)d_in[0];
  const float* qw   = (const float*)d_in[1];
  const float* kw   = (const float*)d_in[2];
  const float* vw   = (const float*)d_in[3];
  const float* frw  = (const float*)d_in[4];
  const float* ffw  = (const float*)d_in[5];
  const float* ffb  = (const float*)d_in[6];
  const float* ln1w = (const float*)d_in[7];
  const float* ln1b = (const float*)d_in[8];
  const float* ln2w = (const float*)d_in[9];
  const float* ln2b = (const float*)d_in[10];
  float* out = (float*)d_out;
  float* ws = (float*)d_ws;

  const size_t NBHF = (size_t)Bc * Hc * Tc * Fc; // 4,194,304 floats
  float* qb = ws;
  float* kb = ws + NBHF;
  float* vb = ws + 2 * NBHF;
  float* zb = ws + 3 * NBHF;
  float* s1 = qb;  // aliases: q dead after attn
  float* z1 = kb;  // k dead after attn
  float* s2 = vb;  // v dead after attn
  float2* part1  = (float2*)(ws + 4 * NBHF);
  float2* part2  = part1 + 1024;
  float2* stats1 = part2 + 1024;
  float2* stats2 = stats1 + 4;

  gemm_proj<<<dim3(64, 16, 3), 256, 0, stream>>>(x, qw, kw, vw, qb, kb, vb);
  attn<<<dim3(256), 256, 0, stream>>>(qb, kb, vb, zb);
  gemm_fr<<<dim3(16, 16, 4), 256, 0, stream>>>(zb, frw, x, s1, part1);
  ln_stats<<<dim3(4), 256, 0, stream>>>(part1, stats1);
  ln_norm<<<dim3(4096), 256, 0, stream>>>(s1, stats1, ln1w, ln1b, z1);
  gemm_ff<<<dim3(64, 16), 256, 0, stream>>>(z1, ffw, ffb, s2, part2);
  ln_stats<<<dim3(4), 256, 0, stream>>>(part2, stats2);
  ln_norm<<<dim3(4096), 256, 0, stream>>>(s2, stats2, ln2w, ln2b, out);
}

// Round 4
// 816.975 us; speedup vs baseline: 1.8134x; 1.8134x over previous
//
#include <hip/hip_runtime.h>
#include <math.h>

constexpr int Bc = 4, Tc = 1024, Ec = 1024, Hc = 16, Fc = 64;

typedef __attribute__((ext_vector_type(8))) short bf16x8;
typedef __attribute__((ext_vector_type(4))) float f32x4;

__device__ __forceinline__ ushort f2bf(float x) {
  union { float f; unsigned u; } v; v.f = x;
  unsigned r = v.u + 0x7fffu + ((v.u >> 16) & 1u);
  return (ushort)(r >> 16);
}
__device__ __forceinline__ float bf2f(ushort h) {
  union { float f; unsigned u; } v; v.u = ((unsigned)h) << 16; return v.f;
}
__device__ __forceinline__ void split3(float x, ushort& h, ushort& m, ushort& l) {
  h = f2bf(x);
  float r1 = x - bf2f(h);
  m = f2bf(r1);
  float r2 = r1 - bf2f(m);
  l = f2bf(r2);
}

// ---------------------------------------------------------------------------
// QKV projection (fp32 VALU GEMM). q,k stored fp32 [bh][t][f] (split to bf16
// on the fly in attn); v stored bf16 TRANSPOSED [bh][f][t] for the PV B-op.
// ---------------------------------------------------------------------------
__global__ __launch_bounds__(256) void gemm_proj(
    const float* __restrict__ x, const float* __restrict__ qw,
    const float* __restrict__ kw, const float* __restrict__ vw,
    float* __restrict__ qf, float* __restrict__ kf, ushort* __restrict__ vt)
{
  const int zi = blockIdx.z;
  const float* w = (zi == 0) ? qw : (zi == 1) ? kw : vw;
  const int m0 = blockIdx.x * 64, n0 = blockIdx.y * 64;
  const int h = n0 >> 6;
  __shared__ float As[16][64], Bs[16][64];
  const int tid = threadIdx.x;
  const int tx = tid & 15, ty = tid >> 4;
  const int arow = tid >> 2, ac4 = tid & 3;
  const int brow = tid >> 4, bc4 = tid & 15;
  float acc[4][4] = {};
  const float* ag = x + (size_t)(m0 + arow) * Ec + ac4 * 4;
  const float* bg = w + (size_t)h * Ec * Fc + (size_t)brow * Fc + bc4 * 4;
  for (int k0 = 0; k0 < Ec; k0 += 16) {
    float4 a = *(const float4*)(ag + k0);
    float4 b = *(const float4*)(bg + (size_t)k0 * Fc);
    __syncthreads();
    As[ac4 * 4 + 0][arow] = a.x; As[ac4 * 4 + 1][arow] = a.y;
    As[ac4 * 4 + 2][arow] = a.z; As[ac4 * 4 + 3][arow] = a.w;
    *(float4*)&Bs[brow][bc4 * 4] = b;
    __syncthreads();
#pragma unroll
    for (int kk = 0; kk < 16; ++kk) {
      float4 av = *(const float4*)&As[kk][ty * 4];
      float4 bv = *(const float4*)&Bs[kk][tx * 4];
      float aa[4] = {av.x, av.y, av.z, av.w};
      float bb[4] = {bv.x, bv.y, bv.z, bv.w};
#pragma unroll
      for (int i = 0; i < 4; ++i)
#pragma unroll
        for (int j = 0; j < 4; ++j) acc[i][j] += aa[i] * bb[j];
    }
  }
  if (zi < 2) {
    float* of = (zi == 0) ? qf : kf;
#pragma unroll
    for (int i = 0; i < 4; ++i) {
      int mrow = m0 + ty * 4 + i;
      int b = mrow >> 10, t = mrow & 1023;
      size_t idx = ((size_t)(b * Hc + h) * Tc + t) * Fc + tx * 4;
      *(float4*)&of[idx] = make_float4(acc[i][0], acc[i][1], acc[i][2], acc[i][3]);
    }
  } else {
#pragma unroll
    for (int i = 0; i < 4; ++i) {
      int mrow = m0 + ty * 4 + i;
      int b = mrow >> 10, t = mrow & 1023;
#pragma unroll
      for (int j = 0; j < 4; ++j) {
        int f = tx * 4 + j;
        vt[((size_t)(b * Hc + h) * Fc + f) * Tc + t] = f2bf(acc[i][j]);
      }
    }
  }
}

// ---------------------------------------------------------------------------
// Flash attention, MFMA 16x16x32 bf16. S = QK^T via 6-product 3-way bf16
// split (fp32-accurate), split done on the fly from fp32 q/k. Multiplicative
// mask (faithful), online softmax per row (rows private to one 16-lane
// group). P -> wave-private LDS -> A-operand; V^T staged in LDS.
// Block: 256 thr = 4 waves x 16 q-rows. Grid: (T/64, B*H).
// ---------------------------------------------------------------------------
__global__ __launch_bounds__(256) void attn_mfma(
    const float* __restrict__ qf, const float* __restrict__ kf,
    const ushort* __restrict__ vt, float* __restrict__ z)
{
  __shared__ ushort Ks[3][64][72];  // [split][key][f], pad 72
  __shared__ ushort Vs[64][72];     // [f][key]
  __shared__ ushort Pl[4][16][72];  // per-wave P region [wave][row][key]

  const int tid = threadIdx.x;
  const int wave = tid >> 6, lane = tid & 63;
  const int l15 = lane & 15, quad = lane >> 4;
  const int bh = blockIdx.y;
  const int qbase = blockIdx.x * 64;

  // Q fragments (A-layout: m=lane&15, k=quad*8+j), split on the fly
  bf16x8 aqh[2], aqm[2], aql[2];
  {
    const int qrow = qbase + wave * 16 + l15;
    const float* qp = qf + ((size_t)bh * Tc + qrow) * Fc;
#pragma unroll
    for (int ks = 0; ks < 2; ++ks) {
      int f0 = ks * 32 + quad * 8;
      float4 x0 = *(const float4*)(qp + f0);
      float4 x1 = *(const float4*)(qp + f0 + 4);
      float xs[8] = {x0.x, x0.y, x0.z, x0.w, x1.x, x1.y, x1.z, x1.w};
#pragma unroll
      for (int j = 0; j < 8; ++j) {
        ushort hu, mu, lu;
        split3(xs[j], hu, mu, lu);
        aqh[ks][j] = (short)hu; aqm[ks][j] = (short)mu; aql[ks][j] = (short)lu;
      }
    }
  }

  f32x4 o[4] = {{0,0,0,0},{0,0,0,0},{0,0,0,0},{0,0,0,0}};
  float m_run[4], l_run[4];
#pragma unroll
  for (int r = 0; r < 4; ++r) { m_run[r] = -1e30f; l_run[r] = 0.f; }

  const int srow = tid >> 2, sc = tid & 3;
  const size_t kbase = (size_t)bh * Tc * Fc;
  const size_t vbase = (size_t)bh * Fc * Tc;

  for (int kt = 0; kt < Tc; kt += 64) {
    __syncthreads();  // protect Ks/Vs against prior-iter readers
    {
      const float* kp = kf + kbase + (size_t)(kt + srow) * Fc + sc * 16;
#pragma unroll
      for (int g = 0; g < 2; ++g) {
        float4 x0 = *(const float4*)(kp + g * 8);
        float4 x1 = *(const float4*)(kp + g * 8 + 4);
        float xs[8] = {x0.x, x0.y, x0.z, x0.w, x1.x, x1.y, x1.z, x1.w};
        bf16x8 hh, mm, ll;
#pragma unroll
        for (int j = 0; j < 8; ++j) {
          ushort hu, mu, lu;
          split3(xs[j], hu, mu, lu);
          hh[j] = (short)hu; mm[j] = (short)mu; ll[j] = (short)lu;
        }
        *(bf16x8*)&Ks[0][srow][sc * 16 + g * 8] = hh;
        *(bf16x8*)&Ks[1][srow][sc * 16 + g * 8] = mm;
        *(bf16x8*)&Ks[2][srow][sc * 16 + g * 8] = ll;
      }
      // V tile: 64x64 ushorts = 16 per thread (NOT 8 — the round-2/3 NaN bug:
      // half the tile was left as uninitialized LDS -> bf16 NaN into PV MFMA)
      size_t gv = vbase + (size_t)srow * Tc + kt + sc * 16;
      *(bf16x8*)&Vs[srow][sc * 16]     = *(const bf16x8*)(vt + gv);
      *(bf16x8*)&Vs[srow][sc * 16 + 8] = *(const bf16x8*)(vt + gv + 8);
    }
    __syncthreads();

    // S tile: 16 rows x 64 keys per wave
    f32x4 sacc[4] = {{0,0,0,0},{0,0,0,0},{0,0,0,0},{0,0,0,0}};
#pragma unroll
    for (int nt = 0; nt < 4; ++nt) {
      int key = nt * 16 + l15;
#pragma unroll
      for (int ks = 0; ks < 2; ++ks) {
        int f0 = ks * 32 + quad * 8;
        bf16x8 bh_ = *(const bf16x8*)&Ks[0][key][f0];
        bf16x8 bm_ = *(const bf16x8*)&Ks[1][key][f0];
        bf16x8 bl_ = *(const bf16x8*)&Ks[2][key][f0];
        sacc[nt] = __builtin_amdgcn_mfma_f32_16x16x32_bf16(aqh[ks], bh_, sacc[nt], 0, 0, 0);
        sacc[nt] = __builtin_amdgcn_mfma_f32_16x16x32_bf16(aqh[ks], bm_, sacc[nt], 0, 0, 0);
        sacc[nt] = __builtin_amdgcn_mfma_f32_16x16x32_bf16(aqm[ks], bh_, sacc[nt], 0, 0, 0);
        sacc[nt] = __builtin_amdgcn_mfma_f32_16x16x32_bf16(aqh[ks], bl_, sacc[nt], 0, 0, 0);
        sacc[nt] = __builtin_amdgcn_mfma_f32_16x16x32_bf16(aqm[ks], bm_, sacc[nt], 0, 0, 0);
        sacc[nt] = __builtin_amdgcn_mfma_f32_16x16x32_bf16(aql[ks], bh_, sacc[nt], 0, 0, 0);
      }
    }

    // mask + scale + online softmax (C/D: col=lane&15, row=quad*4+reg)
    const int rowg0 = qbase + wave * 16 + quad * 4;
    float mx[4];
#pragma unroll
    for (int r = 0; r < 4; ++r) mx[r] = -1e30f;
#pragma unroll
    for (int nt = 0; nt < 4; ++nt) {
      int key = kt + nt * 16 + l15;
#pragma unroll
      for (int r = 0; r < 4; ++r) {
        float s = sacc[nt][r];
        if (key > rowg0 + r) s *= -1.0e9f + 1.0f;  // folds to -1e9f, as jax
        s *= 0.125f;                                // 1/sqrt(F)
        sacc[nt][r] = s;
        mx[r] = fmaxf(mx[r], s);
      }
    }
#pragma unroll
    for (int r = 0; r < 4; ++r)
#pragma unroll
      for (int d = 1; d < 16; d <<= 1) mx[r] = fmaxf(mx[r], __shfl_xor(mx[r], d));

    float corr[4], ps[4];
#pragma unroll
    for (int r = 0; r < 4; ++r) {
      float m2 = fmaxf(m_run[r], mx[r]);
      corr[r] = __expf(m_run[r] - m2);  // 0 on first tile (finite arith)
      m_run[r] = m2;
      ps[r] = 0.f;
    }
#pragma unroll
    for (int nt = 0; nt < 4; ++nt) {
#pragma unroll
      for (int r = 0; r < 4; ++r) {
        float p = __expf(sacc[nt][r] - m_run[r]);  // arg <= 0 always
        ps[r] += p;
        Pl[wave][quad * 4 + r][nt * 16 + l15] = f2bf(p);
      }
    }
#pragma unroll
    for (int r = 0; r < 4; ++r) {
#pragma unroll
      for (int d = 1; d < 16; d <<= 1) ps[r] += __shfl_xor(ps[r], d);
      l_run[r] = l_run[r] * corr[r] + ps[r];
#pragma unroll
      for (int ft = 0; ft < 4; ++ft) o[ft][r] *= corr[r];
    }

    // PV: O(16x64f) += P(16x64k) x V(64k x 64f); P region is wave-private
#pragma unroll
    for (int ks2 = 0; ks2 < 2; ++ks2) {
      bf16x8 pa = *(const bf16x8*)&Pl[wave][l15][ks2 * 32 + quad * 8];
#pragma unroll
      for (int ft = 0; ft < 4; ++ft) {
        bf16x8 vb = *(const bf16x8*)&Vs[ft * 16 + l15][ks2 * 32 + quad * 8];
        o[ft] = __builtin_amdgcn_mfma_f32_16x16x32_bf16(pa, vb, o[ft], 0, 0, 0);
      }
    }
  }

  // epilogue: z[b][t][h*64+f], merged heads
  const int b = bh >> 4, h = bh & 15;
#pragma unroll
  for (int r = 0; r < 4; ++r) {
    float inv = 1.f / l_run[r];
    int row = qbase + wave * 16 + quad * 4 + r;
    float* zp = z + ((size_t)(b * Tc + row)) * Ec + h * Fc;
#pragma unroll
    for (int ft = 0; ft < 4; ++ft) zp[ft * 16 + l15] = o[ft][r] * inv;
  }
}

// ---------------------------------------------------------------------------
// GEMM: per-batch feature reduction + residual + LN1 partials.
// ---------------------------------------------------------------------------
__global__ __launch_bounds__(256) void gemm_fr(
    const float* __restrict__ z, const float* __restrict__ frw,
    const float* __restrict__ x, float* __restrict__ s1,
    float2* __restrict__ part)
{
  const int bb = blockIdx.z;
  const int m0 = blockIdx.x * 64, n0 = blockIdx.y * 64;
  __shared__ float As[16][64], Bs[16][64];
  __shared__ float2 red[256];
  const int tid = threadIdx.x;
  const int tx = tid & 15, ty = tid >> 4;
  const int arow = tid >> 2, ac4 = tid & 3;
  const int brow = tid >> 4, bc4 = tid & 15;
  float acc[4][4] = {};
  const float* ag = z + (size_t)(bb * Tc + m0 + arow) * Ec + ac4 * 4;
  const float* bg = frw + (size_t)bb * Ec * Ec + (size_t)brow * Ec + n0 + bc4 * 4;
  for (int k0 = 0; k0 < Ec; k0 += 16) {
    float4 a = *(const float4*)(ag + k0);
    float4 b = *(const float4*)(bg + (size_t)k0 * Ec);
    __syncthreads();
    As[ac4 * 4 + 0][arow] = a.x; As[ac4 * 4 + 1][arow] = a.y;
    As[ac4 * 4 + 2][arow] = a.z; As[ac4 * 4 + 3][arow] = a.w;
    *(float4*)&Bs[brow][bc4 * 4] = b;
    __syncthreads();
#pragma unroll
    for (int kk = 0; kk < 16; ++kk) {
      float4 av = *(const float4*)&As[kk][ty * 4];
      float4 bv = *(const float4*)&Bs[kk][tx * 4];
      float aa[4] = {av.x, av.y, av.z, av.w};
      float bb2[4] = {bv.x, bv.y, bv.z, bv.w};
#pragma unroll
      for (int i = 0; i < 4; ++i)
#pragma unroll
        for (int j = 0; j < 4; ++j) acc[i][j] += aa[i] * bb2[j];
    }
  }
  float sum = 0.f, sq = 0.f;
#pragma unroll
  for (int i = 0; i < 4; ++i) {
    int m = m0 + ty * 4 + i;
    size_t base = (size_t)(bb * Tc + m) * Ec + n0 + tx * 4;
    float4 xv = *(const float4*)&x[base];
    float4 o = make_float4(xv.x + acc[i][0], xv.y + acc[i][1],
                           xv.z + acc[i][2], xv.w + acc[i][3]);
    *(float4*)&s1[base] = o;
    sum += o.x + o.y + o.z + o.w;
    sq  += o.x * o.x + o.y * o.y + o.z * o.z + o.w * o.w;
  }
  red[tid] = make_float2(sum, sq);
  __syncthreads();
  for (int s = 128; s > 0; s >>= 1) {
    if (tid < s) { red[tid].x += red[tid + s].x; red[tid].y += red[tid + s].y; }
    __syncthreads();
  }
  if (tid == 0) part[(bb * 16 + blockIdx.x) * 16 + blockIdx.y] = red[0];
}

// ---------------------------------------------------------------------------
// GEMM: feed-forward + relu + residual + LN2 partials.
// ---------------------------------------------------------------------------
__global__ __launch_bounds__(256) void gemm_ff(
    const float* __restrict__ z1, const float* __restrict__ ffw,
    const float* __restrict__ ffb, float* __restrict__ s2,
    float2* __restrict__ part)
{
  const int m0 = blockIdx.x * 64, n0 = blockIdx.y * 64;
  __shared__ float As[16][64], Bs[16][64];
  __shared__ float2 red[256];
  const int tid = threadIdx.x;
  const int tx = tid & 15, ty = tid >> 4;
  const int arow = tid >> 2, ac4 = tid & 3;
  float acc[4][4] = {};
  const float* ag = z1 + (size_t)(m0 + arow) * Ec + ac4 * 4;
  const float* bg = ffw + (size_t)(n0 + arow) * Ec + ac4 * 4;
  for (int k0 = 0; k0 < Ec; k0 += 16) {
    float4 a = *(const float4*)(ag + k0);
    float4 b = *(const float4*)(bg + k0);
    __syncthreads();
    As[ac4 * 4 + 0][arow] = a.x; As[ac4 * 4 + 1][arow] = a.y;
    As[ac4 * 4 + 2][arow] = a.z; As[ac4 * 4 + 3][arow] = a.w;
    Bs[ac4 * 4 + 0][arow] = b.x; Bs[ac4 * 4 + 1][arow] = b.y;
    Bs[ac4 * 4 + 2][arow] = b.z; Bs[ac4 * 4 + 3][arow] = b.w;
    __syncthreads();
#pragma unroll
    for (int kk = 0; kk < 16; ++kk) {
      float4 av = *(const float4*)&As[kk][ty * 4];
      float4 bv = *(const float4*)&Bs[kk][tx * 4];
      float aa[4] = {av.x, av.y, av.z, av.w};
      float bb2[4] = {bv.x, bv.y, bv.z, bv.w};
#pragma unroll
      for (int i = 0; i < 4; ++i)
#pragma unroll
        for (int j = 0; j < 4; ++j) acc[i][j] += aa[i] * bb2[j];
    }
  }
  float4 bias = *(const float4*)&ffb[n0 + tx * 4];
  float sum = 0.f, sq = 0.f;
#pragma unroll
  for (int i = 0; i < 4; ++i) {
    int m = m0 + ty * 4 + i;
    size_t base = (size_t)m * Ec + n0 + tx * 4;
    float4 zv = *(const float4*)&z1[base];
    float4 o;
    o.x = zv.x + fmaxf(acc[i][0] + bias.x, 0.f);
    o.y = zv.y + fmaxf(acc[i][1] + bias.y, 0.f);
    o.z = zv.z + fmaxf(acc[i][2] + bias.z, 0.f);
    o.w = zv.w + fmaxf(acc[i][3] + bias.w, 0.f);
    *(float4*)&s2[base] = o;
    sum += o.x + o.y + o.z + o.w;
    sq  += o.x * o.x + o.y * o.y + o.z * o.z + o.w * o.w;
  }
  red[tid] = make_float2(sum, sq);
  __syncthreads();
  for (int s = 128; s > 0; s >>= 1) {
    if (tid < s) { red[tid].x += red[tid + s].x; red[tid].y += red[tid + s].y; }
    __syncthreads();
  }
  if (tid == 0) part[blockIdx.x * 16 + blockIdx.y] = red[0];
}

__global__ __launch_bounds__(256) void ln_stats(
    const float2* __restrict__ part, float2* __restrict__ stats)
{
  __shared__ double sd[256], sq[256];
  const int tid = threadIdx.x;
  float2 p = part[blockIdx.x * 256 + tid];
  sd[tid] = (double)p.x; sq[tid] = (double)p.y;
  __syncthreads();
  for (int s = 128; s > 0; s >>= 1) {
    if (tid < s) { sd[tid] += sd[tid + s]; sq[tid] += sq[tid + s]; }
    __syncthreads();
  }
  if (tid == 0) {
    const double n = (double)Tc * Ec;
    double mean = sd[0] / n;
    double var = sq[0] / n - mean * mean;
    if (var < 0.0) var = 0.0;
    double rs = 1.0 / sqrt(var + 1e-5);
    stats[blockIdx.x] = make_float2((float)mean, (float)rs);
  }
}

__global__ __launch_bounds__(256) void ln_norm(
    const float* __restrict__ s, const float2* __restrict__ stats,
    const float* __restrict__ w, const float* __restrict__ bias,
    float* __restrict__ out)
{
  int i = blockIdx.x * 256 + threadIdx.x;
  if (i >= (Bc * Tc * Ec) / 4) return;
  int b = i >> 18;
  int te4 = i & ((1 << 18) - 1);
  float2 st = stats[b];
  float4 sv = ((const float4*)s)[i];
  float4 wv = ((const float4*)w)[te4];
  float4 bv = ((const float4*)bias)[te4];
  float4 o;
  o.x = (sv.x - st.x) * st.y * wv.x + bv.x;
  o.y = (sv.y - st.x) * st.y * wv.y + bv.y;
  o.z = (sv.z - st.x) * st.y * wv.z + bv.z;
  o.w = (sv.w - st.x) * st.y * wv.w + bv.w;
  ((float4*)out)[i] = o;
}

// ---------------------------------------------------------------------------
extern "C" void kernel_launch(void* const* d_in, const int* in_sizes, int n_in,
                              void* d_out, int out_size, void* d_ws, size_t ws_size,
                              hipStream_t stream)
{
  const float* x    = (const float*)d_in[0];
  const float* qw   = (const float*)d_in[1];
  const float* kw   = (const float*)d_in[2];
  const float* vw   = (const float*)d_in[3];
  const float* frw  = (const float*)d_in[4];
  const float* ffw  = (const float*)d_in[5];
  const float* ffb  = (const float*)d_in[6];
  const float* ln1w = (const float*)d_in[7];
  const float* ln1b = (const float*)d_in[8];
  const float* ln2w = (const float*)d_in[9];
  const float* ln2b = (const float*)d_in[10];
  float* out = (float*)d_out;
  char* W = (char*)d_ws;

  const size_t MB = 1ull << 20;
  // Total footprint: 56 MB + 16.4 KB  (< round-1-proven 64 MB + 16.4 KB)
  float*  qf = (float*)(W);             // 16 MB fp32 [bh][t][f]
  float*  kf = (float*)(W + 16 * MB);   // 16 MB fp32 [bh][t][f]
  ushort* vt = (ushort*)(W + 32 * MB);  //  8 MB bf16 [bh][f][t]
  float*  zb = (float*)(W + 40 * MB);   // 16 MB fp32 [b][t][e]
  float*  s1 = (float*)(W);             // aliases qf (dead after attn)
  float*  z1 = (float*)(W + 16 * MB);   // aliases kf (dead after attn)
  float*  s2 = (float*)(W + 32 * MB);   // aliases vt+zb (dead after gemm_fr)
  float2* part1  = (float2*)(W + 56 * MB);
  float2* part2  = part1 + 1024;
  float2* stats1 = part2 + 1024;
  float2* stats2 = stats1 + 4;

  gemm_proj<<<dim3(64, 16, 3), 256, 0, stream>>>(x, qw, kw, vw, qf, kf, vt);
  attn_mfma<<<dim3(16, 64), 256, 0, stream>>>(qf, kf, vt, zb);
  gemm_fr<<<dim3(16, 16, 4), 256, 0, stream>>>(zb, frw, x, s1, part1);
  ln_stats<<<dim3(4), 256, 0, stream>>>(part1, stats1);
  ln_norm<<<dim3(4096), 256, 0, stream>>>(s1, stats1, ln1w, ln1b, z1);
  gemm_ff<<<dim3(64, 16), 256, 0, stream>>>(z1, ffw, ffb, s2, part2);
  ln_stats<<<dim3(4), 256, 0, stream>>>(part2, stats2);
  ln_norm<<<dim3(4096), 256, 0, stream>>>(s2, stats2, ln2w, ln2b, out);
}

// Round 5
// 628.787 us; speedup vs baseline: 2.3561x; 1.2993x over previous
//
#include <hip/hip_runtime.h>
#include <math.h>

constexpr int Bc = 4, Tc = 1024, Ec = 1024, Hc = 16, Fc = 64;

typedef __attribute__((ext_vector_type(8))) short bf16x8;
typedef __attribute__((ext_vector_type(4))) float f32x4;

__device__ __forceinline__ ushort f2bf(float x) {
  union { float f; unsigned u; } v; v.f = x;
  unsigned r = v.u + 0x7fffu + ((v.u >> 16) & 1u);
  return (ushort)(r >> 16);
}
__device__ __forceinline__ float bf2f(ushort h) {
  union { float f; unsigned u; } v; v.u = ((unsigned)h) << 16; return v.f;
}
__device__ __forceinline__ void split3(float x, ushort& h, ushort& m, ushort& l) {
  h = f2bf(x);
  float r1 = x - bf2f(h);
  m = f2bf(r1);
  float r2 = r1 - bf2f(m);
  l = f2bf(r2);
}

// ---------------------------------------------------------------------------
// Pre-transpose + split the projection weights.
// src w[h][e][f] (fp32) -> wT[s][n=h*64+f][e] (bf16). q at 0, k at 3M, v at 6M
// shorts (v has 1 split). One-time ~14 MB, runs once per launch.
// ---------------------------------------------------------------------------
__global__ __launch_bounds__(256) void transp_w(
    const float* __restrict__ qw, const float* __restrict__ kw,
    const float* __restrict__ vw, ushort* __restrict__ wT)
{
  const int zi = blockIdx.z;
  const float* src = (zi == 0) ? qw : (zi == 1) ? kw : vw;
  ushort* dst = wT + (size_t)(zi * 3) * (1u << 20);
  const int ns = (zi == 2) ? 1 : 3;
  const int h = blockIdx.y, e0 = blockIdx.x * 64;
  __shared__ float T[64][68];
  const int tid = threadIdx.x;
  {
    const int er = tid >> 4, fr = (tid & 15) * 4;
#pragma unroll
    for (int i = 0; i < 4; ++i) {
      const float4 v = *(const float4*)&src[((size_t)(h * 1024 + e0 + er + i * 16)) * 64 + fr];
      *(float4*)&T[er + i * 16][fr] = v;
    }
  }
  __syncthreads();
  const int f = tid >> 2, eo = (tid & 3) * 16;
  ushort hs[16], ms[16], ls[16];
#pragma unroll
  for (int j = 0; j < 16; ++j) {
    split3(T[eo + j][f], hs[j], ms[j], ls[j]);
  }
  const size_t nbase = (size_t)(h * 64 + f) * 1024 + e0 + eo;
  bf16x8 v0, v1;
#pragma unroll
  for (int j = 0; j < 8; ++j) { v0[j] = (short)hs[j]; v1[j] = (short)hs[j + 8]; }
  *(bf16x8*)&dst[nbase] = v0; *(bf16x8*)&dst[nbase + 8] = v1;
  if (ns == 3) {
#pragma unroll
    for (int j = 0; j < 8; ++j) { v0[j] = (short)ms[j]; v1[j] = (short)ms[j + 8]; }
    *(bf16x8*)&dst[(1u << 20) + nbase] = v0; *(bf16x8*)&dst[(1u << 20) + nbase + 8] = v1;
#pragma unroll
    for (int j = 0; j < 8; ++j) { v0[j] = (short)ls[j]; v1[j] = (short)ls[j + 8]; }
    *(bf16x8*)&dst[(2u << 20) + nbase] = v0; *(bf16x8*)&dst[(2u << 20) + nbase + 8] = v1;
  }
}

// ---------------------------------------------------------------------------
// q/k projection: 128x128x(BK=32) MFMA GEMM, split3 x split3, 6 products
// (fp32-equivalent — required to preserve the masked-softmax argmin).
// A = x fp32 (split in staging), B = wT bf16 (pre-split). Grid (32,8,2).
// ---------------------------------------------------------------------------
__global__ __launch_bounds__(256) void proj_qk_mfma(
    const float* __restrict__ x, const ushort* __restrict__ wT,
    float* __restrict__ qf, float* __restrict__ kf)
{
  const int zi = blockIdx.z;
  const ushort* wt = wT + (size_t)zi * 3 * (1u << 20);
  float* of = (zi == 0) ? qf : kf;
  const int m0 = blockIdx.x * 128, n0 = blockIdx.y * 128;
  __shared__ ushort As[3][128][36];
  __shared__ ushort Bs[3][128][36];
  const int tid = threadIdx.x;
  const int wave = tid >> 6, lane = tid & 63, l15 = lane & 15, quad = lane >> 4;
  const int wm = wave >> 1, wn = wave & 1;
  const int sr = tid >> 1, sk = (tid & 1) * 16;  // staging: row, k-offset
  f32x4 acc[4][4] = {};
  for (int k0 = 0; k0 < 1024; k0 += 32) {
    __syncthreads();
    {
      // A: x[m0+sr][k0+sk .. +16], split3 -> As
      const float* ap = x + (size_t)(m0 + sr) * 1024 + k0 + sk;
      float xs[16];
      *(float4*)&xs[0]  = *(const float4*)(ap);
      *(float4*)&xs[4]  = *(const float4*)(ap + 4);
      *(float4*)&xs[8]  = *(const float4*)(ap + 8);
      *(float4*)&xs[12] = *(const float4*)(ap + 12);
      bf16x8 h0, h1, m0v, m1v, l0, l1;
#pragma unroll
      for (int j = 0; j < 8; ++j) {
        ushort hu, mu, lu;
        split3(xs[j], hu, mu, lu);
        h0[j] = (short)hu; m0v[j] = (short)mu; l0[j] = (short)lu;
        split3(xs[j + 8], hu, mu, lu);
        h1[j] = (short)hu; m1v[j] = (short)mu; l1[j] = (short)lu;
      }
      *(bf16x8*)&As[0][sr][sk] = h0;  *(bf16x8*)&As[0][sr][sk + 8] = h1;
      *(bf16x8*)&As[1][sr][sk] = m0v; *(bf16x8*)&As[1][sr][sk + 8] = m1v;
      *(bf16x8*)&As[2][sr][sk] = l0;  *(bf16x8*)&As[2][sr][sk + 8] = l1;
      // B: wT[s][n0+sr][k0+sk ..]
#pragma unroll
      for (int s = 0; s < 3; ++s) {
        const ushort* bp = wt + ((size_t)s << 20) + (size_t)(n0 + sr) * 1024 + k0 + sk;
        *(bf16x8*)&Bs[s][sr][sk]     = *(const bf16x8*)(bp);
        *(bf16x8*)&Bs[s][sr][sk + 8] = *(const bf16x8*)(bp + 8);
      }
    }
    __syncthreads();
    bf16x8 af[4][3];
#pragma unroll
    for (int tm = 0; tm < 4; ++tm)
#pragma unroll
      for (int s = 0; s < 3; ++s)
        af[tm][s] = *(const bf16x8*)&As[s][wm * 64 + tm * 16 + l15][quad * 8];
#pragma unroll
    for (int tn = 0; tn < 4; ++tn) {
      const int nrow = wn * 64 + tn * 16 + l15;
      bf16x8 b0 = *(const bf16x8*)&Bs[0][nrow][quad * 8];
      bf16x8 b1 = *(const bf16x8*)&Bs[1][nrow][quad * 8];
      bf16x8 b2 = *(const bf16x8*)&Bs[2][nrow][quad * 8];
#pragma unroll
      for (int tm = 0; tm < 4; ++tm) {
        f32x4 a = acc[tm][tn];
        a = __builtin_amdgcn_mfma_f32_16x16x32_bf16(af[tm][0], b0, a, 0, 0, 0);
        a = __builtin_amdgcn_mfma_f32_16x16x32_bf16(af[tm][0], b1, a, 0, 0, 0);
        a = __builtin_amdgcn_mfma_f32_16x16x32_bf16(af[tm][1], b0, a, 0, 0, 0);
        a = __builtin_amdgcn_mfma_f32_16x16x32_bf16(af[tm][0], b2, a, 0, 0, 0);
        a = __builtin_amdgcn_mfma_f32_16x16x32_bf16(af[tm][1], b1, a, 0, 0, 0);
        a = __builtin_amdgcn_mfma_f32_16x16x32_bf16(af[tm][2], b0, a, 0, 0, 0);
        acc[tm][tn] = a;
      }
    }
  }
  // epilogue: fp32 [b*16+h][t][f]
#pragma unroll
  for (int tm = 0; tm < 4; ++tm) {
#pragma unroll
    for (int tn = 0; tn < 4; ++tn) {
#pragma unroll
      for (int r = 0; r < 4; ++r) {
        int m = m0 + wm * 64 + tm * 16 + quad * 4 + r;
        int n = n0 + wn * 64 + tn * 16 + l15;
        int b = m >> 10, t = m & 1023, h = n >> 6, f = n & 63;
        of[(((size_t)(b * 16 + h)) * 1024 + t) * 64 + f] = acc[tm][tn][r];
      }
    }
  }
}

// ---------------------------------------------------------------------------
// v projection: plain bf16 MFMA (PV path is bf16 anyway). Writes vt
// transposed [bh][f][t]. Grid (32,8).
// ---------------------------------------------------------------------------
__global__ __launch_bounds__(256) void proj_v_mfma(
    const float* __restrict__ x, const ushort* __restrict__ wT,
    ushort* __restrict__ vt)
{
  const ushort* wt = wT + (size_t)6 * (1u << 20);
  const int m0 = blockIdx.x * 128, n0 = blockIdx.y * 128;
  __shared__ ushort As[128][36];
  __shared__ ushort Bs[128][36];
  const int tid = threadIdx.x;
  const int wave = tid >> 6, lane = tid & 63, l15 = lane & 15, quad = lane >> 4;
  const int wm = wave >> 1, wn = wave & 1;
  const int sr = tid >> 1, sk = (tid & 1) * 16;
  f32x4 acc[4][4] = {};
  for (int k0 = 0; k0 < 1024; k0 += 32) {
    __syncthreads();
    {
      const float* ap = x + (size_t)(m0 + sr) * 1024 + k0 + sk;
      float xs[16];
      *(float4*)&xs[0]  = *(const float4*)(ap);
      *(float4*)&xs[4]  = *(const float4*)(ap + 4);
      *(float4*)&xs[8]  = *(const float4*)(ap + 8);
      *(float4*)&xs[12] = *(const float4*)(ap + 12);
      bf16x8 h0, h1;
#pragma unroll
      for (int j = 0; j < 8; ++j) {
        h0[j] = (short)f2bf(xs[j]);
        h1[j] = (short)f2bf(xs[j + 8]);
      }
      *(bf16x8*)&As[sr][sk] = h0; *(bf16x8*)&As[sr][sk + 8] = h1;
      const ushort* bp = wt + (size_t)(n0 + sr) * 1024 + k0 + sk;
      *(bf16x8*)&Bs[sr][sk]     = *(const bf16x8*)(bp);
      *(bf16x8*)&Bs[sr][sk + 8] = *(const bf16x8*)(bp + 8);
    }
    __syncthreads();
    bf16x8 af[4];
#pragma unroll
    for (int tm = 0; tm < 4; ++tm)
      af[tm] = *(const bf16x8*)&As[wm * 64 + tm * 16 + l15][quad * 8];
#pragma unroll
    for (int tn = 0; tn < 4; ++tn) {
      bf16x8 b0 = *(const bf16x8*)&Bs[wn * 64 + tn * 16 + l15][quad * 8];
#pragma unroll
      for (int tm = 0; tm < 4; ++tm)
        acc[tm][tn] = __builtin_amdgcn_mfma_f32_16x16x32_bf16(af[tm], b0, acc[tm][tn], 0, 0, 0);
    }
  }
#pragma unroll
  for (int tm = 0; tm < 4; ++tm) {
#pragma unroll
    for (int tn = 0; tn < 4; ++tn) {
#pragma unroll
      for (int r = 0; r < 4; ++r) {
        int m = m0 + wm * 64 + tm * 16 + quad * 4 + r;
        int n = n0 + wn * 64 + tn * 16 + l15;
        int b = m >> 10, t = m & 1023, h = n >> 6, f = n & 63;
        vt[(((size_t)(b * 16 + h)) * 64 + f) * 1024 + t] = f2bf(acc[tm][tn][r]);
      }
    }
  }
}

// ---------------------------------------------------------------------------
// Flash attention (unchanged from round 4 — proven).
// ---------------------------------------------------------------------------
__global__ __launch_bounds__(256) void attn_mfma(
    const float* __restrict__ qf, const float* __restrict__ kf,
    const ushort* __restrict__ vt, float* __restrict__ z)
{
  __shared__ ushort Ks[3][64][72];
  __shared__ ushort Vs[64][72];
  __shared__ ushort Pl[4][16][72];

  const int tid = threadIdx.x;
  const int wave = tid >> 6, lane = tid & 63;
  const int l15 = lane & 15, quad = lane >> 4;
  const int bh = blockIdx.y;
  const int qbase = blockIdx.x * 64;

  bf16x8 aqh[2], aqm[2], aql[2];
  {
    const int qrow = qbase + wave * 16 + l15;
    const float* qp = qf + ((size_t)bh * Tc + qrow) * Fc;
#pragma unroll
    for (int ks = 0; ks < 2; ++ks) {
      int f0 = ks * 32 + quad * 8;
      float4 x0 = *(const float4*)(qp + f0);
      float4 x1 = *(const float4*)(qp + f0 + 4);
      float xs[8] = {x0.x, x0.y, x0.z, x0.w, x1.x, x1.y, x1.z, x1.w};
#pragma unroll
      for (int j = 0; j < 8; ++j) {
        ushort hu, mu, lu;
        split3(xs[j], hu, mu, lu);
        aqh[ks][j] = (short)hu; aqm[ks][j] = (short)mu; aql[ks][j] = (short)lu;
      }
    }
  }

  f32x4 o[4] = {{0,0,0,0},{0,0,0,0},{0,0,0,0},{0,0,0,0}};
  float m_run[4], l_run[4];
#pragma unroll
  for (int r = 0; r < 4; ++r) { m_run[r] = -1e30f; l_run[r] = 0.f; }

  const int srow = tid >> 2, sc = tid & 3;
  const size_t kbase = (size_t)bh * Tc * Fc;
  const size_t vbase = (size_t)bh * Fc * Tc;

  for (int kt = 0; kt < Tc; kt += 64) {
    __syncthreads();
    {
      const float* kp = kf + kbase + (size_t)(kt + srow) * Fc + sc * 16;
#pragma unroll
      for (int g = 0; g < 2; ++g) {
        float4 x0 = *(const float4*)(kp + g * 8);
        float4 x1 = *(const float4*)(kp + g * 8 + 4);
        float xs[8] = {x0.x, x0.y, x0.z, x0.w, x1.x, x1.y, x1.z, x1.w};
        bf16x8 hh, mm, ll;
#pragma unroll
        for (int j = 0; j < 8; ++j) {
          ushort hu, mu, lu;
          split3(xs[j], hu, mu, lu);
          hh[j] = (short)hu; mm[j] = (short)mu; ll[j] = (short)lu;
        }
        *(bf16x8*)&Ks[0][srow][sc * 16 + g * 8] = hh;
        *(bf16x8*)&Ks[1][srow][sc * 16 + g * 8] = mm;
        *(bf16x8*)&Ks[2][srow][sc * 16 + g * 8] = ll;
      }
      size_t gv = vbase + (size_t)srow * Tc + kt + sc * 16;
      *(bf16x8*)&Vs[srow][sc * 16]     = *(const bf16x8*)(vt + gv);
      *(bf16x8*)&Vs[srow][sc * 16 + 8] = *(const bf16x8*)(vt + gv + 8);
    }
    __syncthreads();

    f32x4 sacc[4] = {{0,0,0,0},{0,0,0,0},{0,0,0,0},{0,0,0,0}};
#pragma unroll
    for (int nt = 0; nt < 4; ++nt) {
      int key = nt * 16 + l15;
#pragma unroll
      for (int ks = 0; ks < 2; ++ks) {
        int f0 = ks * 32 + quad * 8;
        bf16x8 bh_ = *(const bf16x8*)&Ks[0][key][f0];
        bf16x8 bm_ = *(const bf16x8*)&Ks[1][key][f0];
        bf16x8 bl_ = *(const bf16x8*)&Ks[2][key][f0];
        sacc[nt] = __builtin_amdgcn_mfma_f32_16x16x32_bf16(aqh[ks], bh_, sacc[nt], 0, 0, 0);
        sacc[nt] = __builtin_amdgcn_mfma_f32_16x16x32_bf16(aqh[ks], bm_, sacc[nt], 0, 0, 0);
        sacc[nt] = __builtin_amdgcn_mfma_f32_16x16x32_bf16(aqm[ks], bh_, sacc[nt], 0, 0, 0);
        sacc[nt] = __builtin_amdgcn_mfma_f32_16x16x32_bf16(aqh[ks], bl_, sacc[nt], 0, 0, 0);
        sacc[nt] = __builtin_amdgcn_mfma_f32_16x16x32_bf16(aqm[ks], bm_, sacc[nt], 0, 0, 0);
        sacc[nt] = __builtin_amdgcn_mfma_f32_16x16x32_bf16(aql[ks], bh_, sacc[nt], 0, 0, 0);
      }
    }

    const int rowg0 = qbase + wave * 16 + quad * 4;
    float mx[4];
#pragma unroll
    for (int r = 0; r < 4; ++r) mx[r] = -1e30f;
#pragma unroll
    for (int nt = 0; nt < 4; ++nt) {
      int key = kt + nt * 16 + l15;
#pragma unroll
      for (int r = 0; r < 4; ++r) {
        float s = sacc[nt][r];
        if (key > rowg0 + r) s *= -1.0e9f + 1.0f;
        s *= 0.125f;
        sacc[nt][r] = s;
        mx[r] = fmaxf(mx[r], s);
      }
    }
#pragma unroll
    for (int r = 0; r < 4; ++r)
#pragma unroll
      for (int d = 1; d < 16; d <<= 1) mx[r] = fmaxf(mx[r], __shfl_xor(mx[r], d));

    float corr[4], ps[4];
#pragma unroll
    for (int r = 0; r < 4; ++r) {
      float m2 = fmaxf(m_run[r], mx[r]);
      corr[r] = __expf(m_run[r] - m2);
      m_run[r] = m2;
      ps[r] = 0.f;
    }
#pragma unroll
    for (int nt = 0; nt < 4; ++nt) {
#pragma unroll
      for (int r = 0; r < 4; ++r) {
        float p = __expf(sacc[nt][r] - m_run[r]);
        ps[r] += p;
        Pl[wave][quad * 4 + r][nt * 16 + l15] = f2bf(p);
      }
    }
#pragma unroll
    for (int r = 0; r < 4; ++r) {
#pragma unroll
      for (int d = 1; d < 16; d <<= 1) ps[r] += __shfl_xor(ps[r], d);
      l_run[r] = l_run[r] * corr[r] + ps[r];
#pragma unroll
      for (int ft = 0; ft < 4; ++ft) o[ft][r] *= corr[r];
    }

#pragma unroll
    for (int ks2 = 0; ks2 < 2; ++ks2) {
      bf16x8 pa = *(const bf16x8*)&Pl[wave][l15][ks2 * 32 + quad * 8];
#pragma unroll
      for (int ft = 0; ft < 4; ++ft) {
        bf16x8 vb = *(const bf16x8*)&Vs[ft * 16 + l15][ks2 * 32 + quad * 8];
        o[ft] = __builtin_amdgcn_mfma_f32_16x16x32_bf16(pa, vb, o[ft], 0, 0, 0);
      }
    }
  }

  const int b = bh >> 4, h = bh & 15;
#pragma unroll
  for (int r = 0; r < 4; ++r) {
    float inv = 1.f / l_run[r];
    int row = qbase + wave * 16 + quad * 4 + r;
    float* zp = z + ((size_t)(b * Tc + row)) * Ec + h * Fc;
#pragma unroll
    for (int ft = 0; ft < 4; ++ft) zp[ft * 16 + l15] = o[ft][r] * inv;
  }
}

// ---------------------------------------------------------------------------
// GEMM: per-batch feature reduction + residual + LN1 partials (unchanged).
// ---------------------------------------------------------------------------
__global__ __launch_bounds__(256) void gemm_fr(
    const float* __restrict__ z, const float* __restrict__ frw,
    const float* __restrict__ x, float* __restrict__ s1,
    float2* __restrict__ part)
{
  const int bb = blockIdx.z;
  const int m0 = blockIdx.x * 64, n0 = blockIdx.y * 64;
  __shared__ float As[16][64], Bs[16][64];
  __shared__ float2 red[256];
  const int tid = threadIdx.x;
  const int tx = tid & 15, ty = tid >> 4;
  const int arow = tid >> 2, ac4 = tid & 3;
  const int brow = tid >> 4, bc4 = tid & 15;
  float acc[4][4] = {};
  const float* ag = z + (size_t)(bb * Tc + m0 + arow) * Ec + ac4 * 4;
  const float* bg = frw + (size_t)bb * Ec * Ec + (size_t)brow * Ec + n0 + bc4 * 4;
  for (int k0 = 0; k0 < Ec; k0 += 16) {
    float4 a = *(const float4*)(ag + k0);
    float4 b = *(const float4*)(bg + (size_t)k0 * Ec);
    __syncthreads();
    As[ac4 * 4 + 0][arow] = a.x; As[ac4 * 4 + 1][arow] = a.y;
    As[ac4 * 4 + 2][arow] = a.z; As[ac4 * 4 + 3][arow] = a.w;
    *(float4*)&Bs[brow][bc4 * 4] = b;
    __syncthreads();
#pragma unroll
    for (int kk = 0; kk < 16; ++kk) {
      float4 av = *(const float4*)&As[kk][ty * 4];
      float4 bv = *(const float4*)&Bs[kk][tx * 4];
      float aa[4] = {av.x, av.y, av.z, av.w};
      float bb2[4] = {bv.x, bv.y, bv.z, bv.w};
#pragma unroll
      for (int i = 0; i < 4; ++i)
#pragma unroll
        for (int j = 0; j < 4; ++j) acc[i][j] += aa[i] * bb2[j];
    }
  }
  float sum = 0.f, sq = 0.f;
#pragma unroll
  for (int i = 0; i < 4; ++i) {
    int m = m0 + ty * 4 + i;
    size_t base = (size_t)(bb * Tc + m) * Ec + n0 + tx * 4;
    float4 xv = *(const float4*)&x[base];
    float4 o = make_float4(xv.x + acc[i][0], xv.y + acc[i][1],
                           xv.z + acc[i][2], xv.w + acc[i][3]);
    *(float4*)&s1[base] = o;
    sum += o.x + o.y + o.z + o.w;
    sq  += o.x * o.x + o.y * o.y + o.z * o.z + o.w * o.w;
  }
  red[tid] = make_float2(sum, sq);
  __syncthreads();
  for (int s = 128; s > 0; s >>= 1) {
    if (tid < s) { red[tid].x += red[tid + s].x; red[tid].y += red[tid + s].y; }
    __syncthreads();
  }
  if (tid == 0) part[(bb * 16 + blockIdx.x) * 16 + blockIdx.y] = red[0];
}

// ---------------------------------------------------------------------------
// GEMM: feed-forward + relu + residual + LN2 partials (unchanged).
// ---------------------------------------------------------------------------
__global__ __launch_bounds__(256) void gemm_ff(
    const float* __restrict__ z1, const float* __restrict__ ffw,
    const float* __restrict__ ffb, float* __restrict__ s2,
    float2* __restrict__ part)
{
  const int m0 = blockIdx.x * 64, n0 = blockIdx.y * 64;
  __shared__ float As[16][64], Bs[16][64];
  __shared__ float2 red[256];
  const int tid = threadIdx.x;
  const int tx = tid & 15, ty = tid >> 4;
  const int arow = tid >> 2, ac4 = tid & 3;
  float acc[4][4] = {};
  const float* ag = z1 + (size_t)(m0 + arow) * Ec + ac4 * 4;
  const float* bg = ffw + (size_t)(n0 + arow) * Ec + ac4 * 4;
  for (int k0 = 0; k0 < Ec; k0 += 16) {
    float4 a = *(const float4*)(ag + k0);
    float4 b = *(const float4*)(bg + k0);
    __syncthreads();
    As[ac4 * 4 + 0][arow] = a.x; As[ac4 * 4 + 1][arow] = a.y;
    As[ac4 * 4 + 2][arow] = a.z; As[ac4 * 4 + 3][arow] = a.w;
    Bs[ac4 * 4 + 0][arow] = b.x; Bs[ac4 * 4 + 1][arow] = b.y;
    Bs[ac4 * 4 + 2][arow] = b.z; Bs[ac4 * 4 + 3][arow] = b.w;
    __syncthreads();
#pragma unroll
    for (int kk = 0; kk < 16; ++kk) {
      float4 av = *(const float4*)&As[kk][ty * 4];
      float4 bv = *(const float4*)&Bs[kk][tx * 4];
      float aa[4] = {av.x, av.y, av.z, av.w};
      float bb2[4] = {bv.x, bv.y, bv.z, bv.w};
#pragma unroll
      for (int i = 0; i < 4; ++i)
#pragma unroll
        for (int j = 0; j < 4; ++j) acc[i][j] += aa[i] * bb2[j];
    }
  }
  float4 bias = *(const float4*)&ffb[n0 + tx * 4];
  float sum = 0.f, sq = 0.f;
#pragma unroll
  for (int i = 0; i < 4; ++i) {
    int m = m0 + ty * 4 + i;
    size_t base = (size_t)m * Ec + n0 + tx * 4;
    float4 zv = *(const float4*)&z1[base];
    float4 o;
    o.x = zv.x + fmaxf(acc[i][0] + bias.x, 0.f);
    o.y = zv.y + fmaxf(acc[i][1] + bias.y, 0.f);
    o.z = zv.z + fmaxf(acc[i][2] + bias.z, 0.f);
    o.w = zv.w + fmaxf(acc[i][3] + bias.w, 0.f);
    *(float4*)&s2[base] = o;
    sum += o.x + o.y + o.z + o.w;
    sq  += o.x * o.x + o.y * o.y + o.z * o.z + o.w * o.w;
  }
  red[tid] = make_float2(sum, sq);
  __syncthreads();
  for (int s = 128; s > 0; s >>= 1) {
    if (tid < s) { red[tid].x += red[tid + s].x; red[tid].y += red[tid + s].y; }
    __syncthreads();
  }
  if (tid == 0) part[blockIdx.x * 16 + blockIdx.y] = red[0];
}

__global__ __launch_bounds__(256) void ln_stats(
    const float2* __restrict__ part, float2* __restrict__ stats)
{
  __shared__ double sd[256], sq[256];
  const int tid = threadIdx.x;
  float2 p = part[blockIdx.x * 256 + tid];
  sd[tid] = (double)p.x; sq[tid] = (double)p.y;
  __syncthreads();
  for (int s = 128; s > 0; s >>= 1) {
    if (tid < s) { sd[tid] += sd[tid + s]; sq[tid] += sq[tid + s]; }
    __syncthreads();
  }
  if (tid == 0) {
    const double n = (double)Tc * Ec;
    double mean = sd[0] / n;
    double var = sq[0] / n - mean * mean;
    if (var < 0.0) var = 0.0;
    double rs = 1.0 / sqrt(var + 1e-5);
    stats[blockIdx.x] = make_float2((float)mean, (float)rs);
  }
}

__global__ __launch_bounds__(256) void ln_norm(
    const float* __restrict__ s, const float2* __restrict__ stats,
    const float* __restrict__ w, const float* __restrict__ bias,
    float* __restrict__ out)
{
  int i = blockIdx.x * 256 + threadIdx.x;
  if (i >= (Bc * Tc * Ec) / 4) return;
  int b = i >> 18;
  int te4 = i & ((1 << 18) - 1);
  float2 st = stats[b];
  float4 sv = ((const float4*)s)[i];
  float4 wv = ((const float4*)w)[te4];
  float4 bv = ((const float4*)bias)[te4];
  float4 o;
  o.x = (sv.x - st.x) * st.y * wv.x + bv.x;
  o.y = (sv.y - st.x) * st.y * wv.y + bv.y;
  o.z = (sv.z - st.x) * st.y * wv.z + bv.z;
  o.w = (sv.w - st.x) * st.y * wv.w + bv.w;
  ((float4*)out)[i] = o;
}

// ---------------------------------------------------------------------------
extern "C" void kernel_launch(void* const* d_in, const int* in_sizes, int n_in,
                              void* d_out, int out_size, void* d_ws, size_t ws_size,
                              hipStream_t stream)
{
  const float* x    = (const float*)d_in[0];
  const float* qw   = (const float*)d_in[1];
  const float* kw   = (const float*)d_in[2];
  const float* vw   = (const float*)d_in[3];
  const float* frw  = (const float*)d_in[4];
  const float* ffw  = (const float*)d_in[5];
  const float* ffb  = (const float*)d_in[6];
  const float* ln1w = (const float*)d_in[7];
  const float* ln1b = (const float*)d_in[8];
  const float* ln2w = (const float*)d_in[9];
  const float* ln2b = (const float*)d_in[10];
  float* out = (float*)d_out;
  char* W = (char*)d_ws;

  const size_t MB = 1ull << 20;
  // Footprint: 56 MB + 16.4 KB (= round-4 proven).
  float*  qf = (float*)(W);             // 16 MB fp32 [bh][t][f]
  float*  kf = (float*)(W + 16 * MB);   // 16 MB fp32 [bh][t][f]
  ushort* vt = (ushort*)(W + 32 * MB);  //  8 MB bf16 [bh][f][t]
  float*  zb = (float*)(W + 40 * MB);   // 16 MB fp32 [b][t][e]  (after attn)
  ushort* wT = (ushort*)(W + 40 * MB);  // 14 MB bf16 splits — dead before attn
  float*  s1 = (float*)(W);             // aliases qf
  float*  z1 = (float*)(W + 16 * MB);   // aliases kf
  float*  s2 = (float*)(W + 32 * MB);   // aliases vt+zb
  float2* part1  = (float2*)(W + 56 * MB);
  float2* part2  = part1 + 1024;
  float2* stats1 = part2 + 1024;
  float2* stats2 = stats1 + 4;

  transp_w<<<dim3(16, 16, 3), 256, 0, stream>>>(qw, kw, vw, wT);
  proj_qk_mfma<<<dim3(32, 8, 2), 256, 0, stream>>>(x, wT, qf, kf);
  proj_v_mfma<<<dim3(32, 8), 256, 0, stream>>>(x, wT, vt);
  attn_mfma<<<dim3(16, 64), 256, 0, stream>>>(qf, kf, vt, zb);
  gemm_fr<<<dim3(16, 16, 4), 256, 0, stream>>>(zb, frw, x, s1, part1);
  ln_stats<<<dim3(4), 256, 0, stream>>>(part1, stats1);
  ln_norm<<<dim3(4096), 256, 0, stream>>>(s1, stats1, ln1w, ln1b, z1);
  gemm_ff<<<dim3(64, 16), 256, 0, stream>>>(z1, ffw, ffb, s2, part2);
  ln_stats<<<dim3(4), 256, 0, stream>>>(part2, stats2);
  ln_norm<<<dim3(4096), 256, 0, stream>>>(s2, stats2, ln2w, ln2b, out);
}

// Round 6
// 510.018 us; speedup vs baseline: 2.9048x; 1.2329x over previous
//
#include <hip/hip_runtime.h>
#include <math.h>

constexpr int Bc = 4, Tc = 1024, Ec = 1024, Hc = 16, Fc = 64;

typedef __attribute__((ext_vector_type(8))) short bf16x8;
typedef __attribute__((ext_vector_type(4))) float f32x4;

__device__ __forceinline__ ushort f2bf(float x) {
  union { float f; unsigned u; } v; v.f = x;
  unsigned r = v.u + 0x7fffu + ((v.u >> 16) & 1u);
  return (ushort)(r >> 16);
}
__device__ __forceinline__ float bf2f(ushort h) {
  union { float f; unsigned u; } v; v.u = ((unsigned)h) << 16; return v.f;
}
__device__ __forceinline__ void split3(float x, ushort& h, ushort& m, ushort& l) {
  h = f2bf(x);
  float r1 = x - bf2f(h);
  m = f2bf(r1);
  float r2 = r1 - bf2f(m);
  l = f2bf(r2);
}
__device__ __forceinline__ void split2(float x, ushort& h, ushort& l) {
  h = f2bf(x);
  l = f2bf(x - bf2f(h));
}

// ---------------------------------------------------------------------------
// Pre-transpose + split projection weights (unchanged from round 5).
// ---------------------------------------------------------------------------
__global__ __launch_bounds__(256) void transp_w(
    const float* __restrict__ qw, const float* __restrict__ kw,
    const float* __restrict__ vw, ushort* __restrict__ wT)
{
  const int zi = blockIdx.z;
  const float* src = (zi == 0) ? qw : (zi == 1) ? kw : vw;
  ushort* dst = wT + (size_t)(zi * 3) * (1u << 20);
  const int ns = (zi == 2) ? 1 : 3;
  const int h = blockIdx.y, e0 = blockIdx.x * 64;
  __shared__ float T[64][68];
  const int tid = threadIdx.x;
  {
    const int er = tid >> 4, fr = (tid & 15) * 4;
#pragma unroll
    for (int i = 0; i < 4; ++i) {
      const float4 v = *(const float4*)&src[((size_t)(h * 1024 + e0 + er + i * 16)) * 64 + fr];
      *(float4*)&T[er + i * 16][fr] = v;
    }
  }
  __syncthreads();
  const int f = tid >> 2, eo = (tid & 3) * 16;
  ushort hs[16], ms[16], ls[16];
#pragma unroll
  for (int j = 0; j < 16; ++j) {
    split3(T[eo + j][f], hs[j], ms[j], ls[j]);
  }
  const size_t nbase = (size_t)(h * 64 + f) * 1024 + e0 + eo;
  bf16x8 v0, v1;
#pragma unroll
  for (int j = 0; j < 8; ++j) { v0[j] = (short)hs[j]; v1[j] = (short)hs[j + 8]; }
  *(bf16x8*)&dst[nbase] = v0; *(bf16x8*)&dst[nbase + 8] = v1;
  if (ns == 3) {
#pragma unroll
    for (int j = 0; j < 8; ++j) { v0[j] = (short)ms[j]; v1[j] = (short)ms[j + 8]; }
    *(bf16x8*)&dst[(1u << 20) + nbase] = v0; *(bf16x8*)&dst[(1u << 20) + nbase + 8] = v1;
#pragma unroll
    for (int j = 0; j < 8; ++j) { v0[j] = (short)ls[j]; v1[j] = (short)ls[j + 8]; }
    *(bf16x8*)&dst[(2u << 20) + nbase] = v0; *(bf16x8*)&dst[(2u << 20) + nbase + 8] = v1;
  }
}

// ---------------------------------------------------------------------------
// Pre-transpose + split2 fr weights: frw[b][e][d] fp32 -> hi/lo [b][d][e] bf16.
// hi at frT, lo at frT + 4M. Grid (16,16,4).
// ---------------------------------------------------------------------------
__global__ __launch_bounds__(256) void transp_frw(
    const float* __restrict__ frw, ushort* __restrict__ frT)
{
  const int bb = blockIdx.z;
  const int e0 = blockIdx.x * 64, d0 = blockIdx.y * 64;
  __shared__ float T[64][68];
  const int tid = threadIdx.x;
  {
    const int er = tid >> 4, dr = (tid & 15) * 4;
#pragma unroll
    for (int i = 0; i < 4; ++i) {
      const float4 v = *(const float4*)&frw[((size_t)bb * 1024 + e0 + er + i * 16) * 1024 + d0 + dr];
      *(float4*)&T[er + i * 16][dr] = v;
    }
  }
  __syncthreads();
  const int d = tid >> 2, eo = (tid & 3) * 16;
  ushort hs[16], ls[16];
#pragma unroll
  for (int j = 0; j < 16; ++j) split2(T[eo + j][d], hs[j], ls[j]);
  const size_t nbase = ((size_t)bb * 1024 + d0 + d) * 1024 + e0 + eo;
  bf16x8 v0, v1;
#pragma unroll
  for (int j = 0; j < 8; ++j) { v0[j] = (short)hs[j]; v1[j] = (short)hs[j + 8]; }
  *(bf16x8*)&frT[nbase] = v0; *(bf16x8*)&frT[nbase + 8] = v1;
#pragma unroll
  for (int j = 0; j < 8; ++j) { v0[j] = (short)ls[j]; v1[j] = (short)ls[j + 8]; }
  *(bf16x8*)&frT[(4u << 20) + nbase] = v0; *(bf16x8*)&frT[(4u << 20) + nbase + 8] = v1;
}

// ---------------------------------------------------------------------------
// q/k projection MFMA (unchanged from round 5).
// ---------------------------------------------------------------------------
__global__ __launch_bounds__(256) void proj_qk_mfma(
    const float* __restrict__ x, const ushort* __restrict__ wT,
    float* __restrict__ qf, float* __restrict__ kf)
{
  const int zi = blockIdx.z;
  const ushort* wt = wT + (size_t)zi * 3 * (1u << 20);
  float* of = (zi == 0) ? qf : kf;
  const int m0 = blockIdx.x * 128, n0 = blockIdx.y * 128;
  __shared__ ushort As[3][128][36];
  __shared__ ushort Bs[3][128][36];
  const int tid = threadIdx.x;
  const int wave = tid >> 6, lane = tid & 63, l15 = lane & 15, quad = lane >> 4;
  const int wm = wave >> 1, wn = wave & 1;
  const int sr = tid >> 1, sk = (tid & 1) * 16;
  f32x4 acc[4][4] = {};
  for (int k0 = 0; k0 < 1024; k0 += 32) {
    __syncthreads();
    {
      const float* ap = x + (size_t)(m0 + sr) * 1024 + k0 + sk;
      float xs[16];
      *(float4*)&xs[0]  = *(const float4*)(ap);
      *(float4*)&xs[4]  = *(const float4*)(ap + 4);
      *(float4*)&xs[8]  = *(const float4*)(ap + 8);
      *(float4*)&xs[12] = *(const float4*)(ap + 12);
      bf16x8 h0, h1, m0v, m1v, l0, l1;
#pragma unroll
      for (int j = 0; j < 8; ++j) {
        ushort hu, mu, lu;
        split3(xs[j], hu, mu, lu);
        h0[j] = (short)hu; m0v[j] = (short)mu; l0[j] = (short)lu;
        split3(xs[j + 8], hu, mu, lu);
        h1[j] = (short)hu; m1v[j] = (short)mu; l1[j] = (short)lu;
      }
      *(bf16x8*)&As[0][sr][sk] = h0;  *(bf16x8*)&As[0][sr][sk + 8] = h1;
      *(bf16x8*)&As[1][sr][sk] = m0v; *(bf16x8*)&As[1][sr][sk + 8] = m1v;
      *(bf16x8*)&As[2][sr][sk] = l0;  *(bf16x8*)&As[2][sr][sk + 8] = l1;
#pragma unroll
      for (int s = 0; s < 3; ++s) {
        const ushort* bp = wt + ((size_t)s << 20) + (size_t)(n0 + sr) * 1024 + k0 + sk;
        *(bf16x8*)&Bs[s][sr][sk]     = *(const bf16x8*)(bp);
        *(bf16x8*)&Bs[s][sr][sk + 8] = *(const bf16x8*)(bp + 8);
      }
    }
    __syncthreads();
    bf16x8 af[4][3];
#pragma unroll
    for (int tm = 0; tm < 4; ++tm)
#pragma unroll
      for (int s = 0; s < 3; ++s)
        af[tm][s] = *(const bf16x8*)&As[s][wm * 64 + tm * 16 + l15][quad * 8];
#pragma unroll
    for (int tn = 0; tn < 4; ++tn) {
      const int nrow = wn * 64 + tn * 16 + l15;
      bf16x8 b0 = *(const bf16x8*)&Bs[0][nrow][quad * 8];
      bf16x8 b1 = *(const bf16x8*)&Bs[1][nrow][quad * 8];
      bf16x8 b2 = *(const bf16x8*)&Bs[2][nrow][quad * 8];
#pragma unroll
      for (int tm = 0; tm < 4; ++tm) {
        f32x4 a = acc[tm][tn];
        a = __builtin_amdgcn_mfma_f32_16x16x32_bf16(af[tm][0], b0, a, 0, 0, 0);
        a = __builtin_amdgcn_mfma_f32_16x16x32_bf16(af[tm][0], b1, a, 0, 0, 0);
        a = __builtin_amdgcn_mfma_f32_16x16x32_bf16(af[tm][1], b0, a, 0, 0, 0);
        a = __builtin_amdgcn_mfma_f32_16x16x32_bf16(af[tm][0], b2, a, 0, 0, 0);
        a = __builtin_amdgcn_mfma_f32_16x16x32_bf16(af[tm][1], b1, a, 0, 0, 0);
        a = __builtin_amdgcn_mfma_f32_16x16x32_bf16(af[tm][2], b0, a, 0, 0, 0);
        acc[tm][tn] = a;
      }
    }
  }
#pragma unroll
  for (int tm = 0; tm < 4; ++tm) {
#pragma unroll
    for (int tn = 0; tn < 4; ++tn) {
#pragma unroll
      for (int r = 0; r < 4; ++r) {
        int m = m0 + wm * 64 + tm * 16 + quad * 4 + r;
        int n = n0 + wn * 64 + tn * 16 + l15;
        int b = m >> 10, t = m & 1023, h = n >> 6, f = n & 63;
        of[(((size_t)(b * 16 + h)) * 1024 + t) * 64 + f] = acc[tm][tn][r];
      }
    }
  }
}

// ---------------------------------------------------------------------------
// v projection MFMA (unchanged from round 5).
// ---------------------------------------------------------------------------
__global__ __launch_bounds__(256) void proj_v_mfma(
    const float* __restrict__ x, const ushort* __restrict__ wT,
    ushort* __restrict__ vt)
{
  const ushort* wt = wT + (size_t)6 * (1u << 20);
  const int m0 = blockIdx.x * 128, n0 = blockIdx.y * 128;
  __shared__ ushort As[128][36];
  __shared__ ushort Bs[128][36];
  const int tid = threadIdx.x;
  const int wave = tid >> 6, lane = tid & 63, l15 = lane & 15, quad = lane >> 4;
  const int wm = wave >> 1, wn = wave & 1;
  const int sr = tid >> 1, sk = (tid & 1) * 16;
  f32x4 acc[4][4] = {};
  for (int k0 = 0; k0 < 1024; k0 += 32) {
    __syncthreads();
    {
      const float* ap = x + (size_t)(m0 + sr) * 1024 + k0 + sk;
      float xs[16];
      *(float4*)&xs[0]  = *(const float4*)(ap);
      *(float4*)&xs[4]  = *(const float4*)(ap + 4);
      *(float4*)&xs[8]  = *(const float4*)(ap + 8);
      *(float4*)&xs[12] = *(const float4*)(ap + 12);
      bf16x8 h0, h1;
#pragma unroll
      for (int j = 0; j < 8; ++j) {
        h0[j] = (short)f2bf(xs[j]);
        h1[j] = (short)f2bf(xs[j + 8]);
      }
      *(bf16x8*)&As[sr][sk] = h0; *(bf16x8*)&As[sr][sk + 8] = h1;
      const ushort* bp = wt + (size_t)(n0 + sr) * 1024 + k0 + sk;
      *(bf16x8*)&Bs[sr][sk]     = *(const bf16x8*)(bp);
      *(bf16x8*)&Bs[sr][sk + 8] = *(const bf16x8*)(bp + 8);
    }
    __syncthreads();
    bf16x8 af[4];
#pragma unroll
    for (int tm = 0; tm < 4; ++tm)
      af[tm] = *(const bf16x8*)&As[wm * 64 + tm * 16 + l15][quad * 8];
#pragma unroll
    for (int tn = 0; tn < 4; ++tn) {
      bf16x8 b0 = *(const bf16x8*)&Bs[wn * 64 + tn * 16 + l15][quad * 8];
#pragma unroll
      for (int tm = 0; tm < 4; ++tm)
        acc[tm][tn] = __builtin_amdgcn_mfma_f32_16x16x32_bf16(af[tm], b0, acc[tm][tn], 0, 0, 0);
    }
  }
#pragma unroll
  for (int tm = 0; tm < 4; ++tm) {
#pragma unroll
    for (int tn = 0; tn < 4; ++tn) {
#pragma unroll
      for (int r = 0; r < 4; ++r) {
        int m = m0 + wm * 64 + tm * 16 + quad * 4 + r;
        int n = n0 + wn * 64 + tn * 16 + l15;
        int b = m >> 10, t = m & 1023, h = n >> 6, f = n & 63;
        vt[(((size_t)(b * 16 + h)) * 64 + f) * 1024 + t] = f2bf(acc[tm][tn][r]);
      }
    }
  }
}

// ---------------------------------------------------------------------------
// Flash attention (unchanged from round 4 — proven).
// ---------------------------------------------------------------------------
__global__ __launch_bounds__(256) void attn_mfma(
    const float* __restrict__ qf, const float* __restrict__ kf,
    const ushort* __restrict__ vt, float* __restrict__ z)
{
  __shared__ ushort Ks[3][64][72];
  __shared__ ushort Vs[64][72];
  __shared__ ushort Pl[4][16][72];

  const int tid = threadIdx.x;
  const int wave = tid >> 6, lane = tid & 63;
  const int l15 = lane & 15, quad = lane >> 4;
  const int bh = blockIdx.y;
  const int qbase = blockIdx.x * 64;

  bf16x8 aqh[2], aqm[2], aql[2];
  {
    const int qrow = qbase + wave * 16 + l15;
    const float* qp = qf + ((size_t)bh * Tc + qrow) * Fc;
#pragma unroll
    for (int ks = 0; ks < 2; ++ks) {
      int f0 = ks * 32 + quad * 8;
      float4 x0 = *(const float4*)(qp + f0);
      float4 x1 = *(const float4*)(qp + f0 + 4);
      float xs[8] = {x0.x, x0.y, x0.z, x0.w, x1.x, x1.y, x1.z, x1.w};
#pragma unroll
      for (int j = 0; j < 8; ++j) {
        ushort hu, mu, lu;
        split3(xs[j], hu, mu, lu);
        aqh[ks][j] = (short)hu; aqm[ks][j] = (short)mu; aql[ks][j] = (short)lu;
      }
    }
  }

  f32x4 o[4] = {{0,0,0,0},{0,0,0,0},{0,0,0,0},{0,0,0,0}};
  float m_run[4], l_run[4];
#pragma unroll
  for (int r = 0; r < 4; ++r) { m_run[r] = -1e30f; l_run[r] = 0.f; }

  const int srow = tid >> 2, sc = tid & 3;
  const size_t kbase = (size_t)bh * Tc * Fc;
  const size_t vbase = (size_t)bh * Fc * Tc;

  for (int kt = 0; kt < Tc; kt += 64) {
    __syncthreads();
    {
      const float* kp = kf + kbase + (size_t)(kt + srow) * Fc + sc * 16;
#pragma unroll
      for (int g = 0; g < 2; ++g) {
        float4 x0 = *(const float4*)(kp + g * 8);
        float4 x1 = *(const float4*)(kp + g * 8 + 4);
        float xs[8] = {x0.x, x0.y, x0.z, x0.w, x1.x, x1.y, x1.z, x1.w};
        bf16x8 hh, mm, ll;
#pragma unroll
        for (int j = 0; j < 8; ++j) {
          ushort hu, mu, lu;
          split3(xs[j], hu, mu, lu);
          hh[j] = (short)hu; mm[j] = (short)mu; ll[j] = (short)lu;
        }
        *(bf16x8*)&Ks[0][srow][sc * 16 + g * 8] = hh;
        *(bf16x8*)&Ks[1][srow][sc * 16 + g * 8] = mm;
        *(bf16x8*)&Ks[2][srow][sc * 16 + g * 8] = ll;
      }
      size_t gv = vbase + (size_t)srow * Tc + kt + sc * 16;
      *(bf16x8*)&Vs[srow][sc * 16]     = *(const bf16x8*)(vt + gv);
      *(bf16x8*)&Vs[srow][sc * 16 + 8] = *(const bf16x8*)(vt + gv + 8);
    }
    __syncthreads();

    f32x4 sacc[4] = {{0,0,0,0},{0,0,0,0},{0,0,0,0},{0,0,0,0}};
#pragma unroll
    for (int nt = 0; nt < 4; ++nt) {
      int key = nt * 16 + l15;
#pragma unroll
      for (int ks = 0; ks < 2; ++ks) {
        int f0 = ks * 32 + quad * 8;
        bf16x8 bh_ = *(const bf16x8*)&Ks[0][key][f0];
        bf16x8 bm_ = *(const bf16x8*)&Ks[1][key][f0];
        bf16x8 bl_ = *(const bf16x8*)&Ks[2][key][f0];
        sacc[nt] = __builtin_amdgcn_mfma_f32_16x16x32_bf16(aqh[ks], bh_, sacc[nt], 0, 0, 0);
        sacc[nt] = __builtin_amdgcn_mfma_f32_16x16x32_bf16(aqh[ks], bm_, sacc[nt], 0, 0, 0);
        sacc[nt] = __builtin_amdgcn_mfma_f32_16x16x32_bf16(aqm[ks], bh_, sacc[nt], 0, 0, 0);
        sacc[nt] = __builtin_amdgcn_mfma_f32_16x16x32_bf16(aqh[ks], bl_, sacc[nt], 0, 0, 0);
        sacc[nt] = __builtin_amdgcn_mfma_f32_16x16x32_bf16(aqm[ks], bm_, sacc[nt], 0, 0, 0);
        sacc[nt] = __builtin_amdgcn_mfma_f32_16x16x32_bf16(aql[ks], bh_, sacc[nt], 0, 0, 0);
      }
    }

    const int rowg0 = qbase + wave * 16 + quad * 4;
    float mx[4];
#pragma unroll
    for (int r = 0; r < 4; ++r) mx[r] = -1e30f;
#pragma unroll
    for (int nt = 0; nt < 4; ++nt) {
      int key = kt + nt * 16 + l15;
#pragma unroll
      for (int r = 0; r < 4; ++r) {
        float s = sacc[nt][r];
        if (key > rowg0 + r) s *= -1.0e9f + 1.0f;
        s *= 0.125f;
        sacc[nt][r] = s;
        mx[r] = fmaxf(mx[r], s);
      }
    }
#pragma unroll
    for (int r = 0; r < 4; ++r)
#pragma unroll
      for (int d = 1; d < 16; d <<= 1) mx[r] = fmaxf(mx[r], __shfl_xor(mx[r], d));

    float corr[4], ps[4];
#pragma unroll
    for (int r = 0; r < 4; ++r) {
      float m2 = fmaxf(m_run[r], mx[r]);
      corr[r] = __expf(m_run[r] - m2);
      m_run[r] = m2;
      ps[r] = 0.f;
    }
#pragma unroll
    for (int nt = 0; nt < 4; ++nt) {
#pragma unroll
      for (int r = 0; r < 4; ++r) {
        float p = __expf(sacc[nt][r] - m_run[r]);
        ps[r] += p;
        Pl[wave][quad * 4 + r][nt * 16 + l15] = f2bf(p);
      }
    }
#pragma unroll
    for (int r = 0; r < 4; ++r) {
#pragma unroll
      for (int d = 1; d < 16; d <<= 1) ps[r] += __shfl_xor(ps[r], d);
      l_run[r] = l_run[r] * corr[r] + ps[r];
#pragma unroll
      for (int ft = 0; ft < 4; ++ft) o[ft][r] *= corr[r];
    }

#pragma unroll
    for (int ks2 = 0; ks2 < 2; ++ks2) {
      bf16x8 pa = *(const bf16x8*)&Pl[wave][l15][ks2 * 32 + quad * 8];
#pragma unroll
      for (int ft = 0; ft < 4; ++ft) {
        bf16x8 vb = *(const bf16x8*)&Vs[ft * 16 + l15][ks2 * 32 + quad * 8];
        o[ft] = __builtin_amdgcn_mfma_f32_16x16x32_bf16(pa, vb, o[ft], 0, 0, 0);
      }
    }
  }

  const int b = bh >> 4, h = bh & 15;
#pragma unroll
  for (int r = 0; r < 4; ++r) {
    float inv = 1.f / l_run[r];
    int row = qbase + wave * 16 + quad * 4 + r;
    float* zp = z + ((size_t)(b * Tc + row)) * Ec + h * Fc;
#pragma unroll
    for (int ft = 0; ft < 4; ++ft) zp[ft * 16 + l15] = o[ft][r] * inv;
  }
}

// ---------------------------------------------------------------------------
// fr GEMM, split2 MFMA (3 products): s1 = x + z*frw, + LN1 partials.
// A = z fp32 (split2 in staging), B = frT pre-split [b][d][e]. Grid (8,8,4).
// ---------------------------------------------------------------------------
__global__ __launch_bounds__(256) void gemm_fr_mfma(
    const float* __restrict__ z, const ushort* __restrict__ frT,
    const float* __restrict__ x, float* __restrict__ s1,
    float2* __restrict__ part)
{
  const int bb = blockIdx.z;
  const int m0 = blockIdx.x * 128, n0 = blockIdx.y * 128;
  __shared__ ushort Ah[128][36], Al[128][36];
  __shared__ ushort Bh[128][36], Bl[128][36];
  __shared__ float2 red[256];
  const int tid = threadIdx.x;
  const int wave = tid >> 6, lane = tid & 63, l15 = lane & 15, quad = lane >> 4;
  const int wm = wave >> 1, wn = wave & 1;
  const int sr = tid >> 1, sk = (tid & 1) * 16;
  f32x4 acc[4][4] = {};
  const ushort* bhp = frT + ((size_t)bb * 1024 + n0) * 1024;
  const ushort* blp = bhp + (4u << 20);
  for (int k0 = 0; k0 < 1024; k0 += 32) {
    __syncthreads();
    {
      const float* ap = z + ((size_t)bb * 1024 + m0 + sr) * 1024 + k0 + sk;
      float xs[16];
      *(float4*)&xs[0]  = *(const float4*)(ap);
      *(float4*)&xs[4]  = *(const float4*)(ap + 4);
      *(float4*)&xs[8]  = *(const float4*)(ap + 8);
      *(float4*)&xs[12] = *(const float4*)(ap + 12);
      bf16x8 h0, h1, l0, l1;
#pragma unroll
      for (int j = 0; j < 8; ++j) {
        ushort hu, lu;
        split2(xs[j], hu, lu);     h0[j] = (short)hu; l0[j] = (short)lu;
        split2(xs[j + 8], hu, lu); h1[j] = (short)hu; l1[j] = (short)lu;
      }
      *(bf16x8*)&Ah[sr][sk] = h0; *(bf16x8*)&Ah[sr][sk + 8] = h1;
      *(bf16x8*)&Al[sr][sk] = l0; *(bf16x8*)&Al[sr][sk + 8] = l1;
      const size_t boff = (size_t)sr * 1024 + k0 + sk;
      *(bf16x8*)&Bh[sr][sk]     = *(const bf16x8*)(bhp + boff);
      *(bf16x8*)&Bh[sr][sk + 8] = *(const bf16x8*)(bhp + boff + 8);
      *(bf16x8*)&Bl[sr][sk]     = *(const bf16x8*)(blp + boff);
      *(bf16x8*)&Bl[sr][sk + 8] = *(const bf16x8*)(blp + boff + 8);
    }
    __syncthreads();
    bf16x8 ah[4], al[4];
#pragma unroll
    for (int tm = 0; tm < 4; ++tm) {
      ah[tm] = *(const bf16x8*)&Ah[wm * 64 + tm * 16 + l15][quad * 8];
      al[tm] = *(const bf16x8*)&Al[wm * 64 + tm * 16 + l15][quad * 8];
    }
#pragma unroll
    for (int tn = 0; tn < 4; ++tn) {
      const int nrow = wn * 64 + tn * 16 + l15;
      bf16x8 b0 = *(const bf16x8*)&Bh[nrow][quad * 8];
      bf16x8 b1 = *(const bf16x8*)&Bl[nrow][quad * 8];
#pragma unroll
      for (int tm = 0; tm < 4; ++tm) {
        f32x4 a = acc[tm][tn];
        a = __builtin_amdgcn_mfma_f32_16x16x32_bf16(ah[tm], b0, a, 0, 0, 0);
        a = __builtin_amdgcn_mfma_f32_16x16x32_bf16(ah[tm], b1, a, 0, 0, 0);
        a = __builtin_amdgcn_mfma_f32_16x16x32_bf16(al[tm], b0, a, 0, 0, 0);
        acc[tm][tn] = a;
      }
    }
  }
  float sum = 0.f, sq = 0.f;
#pragma unroll
  for (int tm = 0; tm < 4; ++tm) {
#pragma unroll
    for (int tn = 0; tn < 4; ++tn) {
#pragma unroll
      for (int r = 0; r < 4; ++r) {
        int m = m0 + wm * 64 + tm * 16 + quad * 4 + r;
        int n = n0 + wn * 64 + tn * 16 + l15;
        size_t idx = ((size_t)bb * 1024 + m) * 1024 + n;
        float o = x[idx] + acc[tm][tn][r];
        s1[idx] = o;
        sum += o; sq += o * o;
      }
    }
  }
  red[tid] = make_float2(sum, sq);
  __syncthreads();
  for (int s = 128; s > 0; s >>= 1) {
    if (tid < s) { red[tid].x += red[tid + s].x; red[tid].y += red[tid + s].y; }
    __syncthreads();
  }
  if (tid == 0) part[(bb * 8 + blockIdx.x) * 8 + blockIdx.y] = red[0];
}

// ---------------------------------------------------------------------------
// ff GEMM, split2 MFMA (3 products): s2 = z1 + relu(z1*ffw^T + ffb), + LN2
// partials. B = ffw [d][e] fp32 split2 in staging (no transpose). Grid (32,8).
// ---------------------------------------------------------------------------
__global__ __launch_bounds__(256) void gemm_ff_mfma(
    const float* __restrict__ z1, const float* __restrict__ ffw,
    const float* __restrict__ ffb, float* __restrict__ s2,
    float2* __restrict__ part)
{
  const int m0 = blockIdx.x * 128, n0 = blockIdx.y * 128;
  __shared__ ushort Ah[128][36], Al[128][36];
  __shared__ ushort Bh[128][36], Bl[128][36];
  __shared__ float2 red[256];
  const int tid = threadIdx.x;
  const int wave = tid >> 6, lane = tid & 63, l15 = lane & 15, quad = lane >> 4;
  const int wm = wave >> 1, wn = wave & 1;
  const int sr = tid >> 1, sk = (tid & 1) * 16;
  f32x4 acc[4][4] = {};
  for (int k0 = 0; k0 < 1024; k0 += 32) {
    __syncthreads();
    {
      const float* ap = z1 + (size_t)(m0 + sr) * 1024 + k0 + sk;
      const float* bp = ffw + (size_t)(n0 + sr) * 1024 + k0 + sk;
      float xs[16], ys[16];
      *(float4*)&xs[0]  = *(const float4*)(ap);
      *(float4*)&xs[4]  = *(const float4*)(ap + 4);
      *(float4*)&xs[8]  = *(const float4*)(ap + 8);
      *(float4*)&xs[12] = *(const float4*)(ap + 12);
      *(float4*)&ys[0]  = *(const float4*)(bp);
      *(float4*)&ys[4]  = *(const float4*)(bp + 4);
      *(float4*)&ys[8]  = *(const float4*)(bp + 8);
      *(float4*)&ys[12] = *(const float4*)(bp + 12);
      bf16x8 h0, h1, l0, l1, g0, g1, e0, e1;
#pragma unroll
      for (int j = 0; j < 8; ++j) {
        ushort hu, lu;
        split2(xs[j], hu, lu);     h0[j] = (short)hu; l0[j] = (short)lu;
        split2(xs[j + 8], hu, lu); h1[j] = (short)hu; l1[j] = (short)lu;
        split2(ys[j], hu, lu);     g0[j] = (short)hu; e0[j] = (short)lu;
        split2(ys[j + 8], hu, lu); g1[j] = (short)hu; e1[j] = (short)lu;
      }
      *(bf16x8*)&Ah[sr][sk] = h0; *(bf16x8*)&Ah[sr][sk + 8] = h1;
      *(bf16x8*)&Al[sr][sk] = l0; *(bf16x8*)&Al[sr][sk + 8] = l1;
      *(bf16x8*)&Bh[sr][sk] = g0; *(bf16x8*)&Bh[sr][sk + 8] = g1;
      *(bf16x8*)&Bl[sr][sk] = e0; *(bf16x8*)&Bl[sr][sk + 8] = e1;
    }
    __syncthreads();
    bf16x8 ah[4], al[4];
#pragma unroll
    for (int tm = 0; tm < 4; ++tm) {
      ah[tm] = *(const bf16x8*)&Ah[wm * 64 + tm * 16 + l15][quad * 8];
      al[tm] = *(const bf16x8*)&Al[wm * 64 + tm * 16 + l15][quad * 8];
    }
#pragma unroll
    for (int tn = 0; tn < 4; ++tn) {
      const int nrow = wn * 64 + tn * 16 + l15;
      bf16x8 b0 = *(const bf16x8*)&Bh[nrow][quad * 8];
      bf16x8 b1 = *(const bf16x8*)&Bl[nrow][quad * 8];
#pragma unroll
      for (int tm = 0; tm < 4; ++tm) {
        f32x4 a = acc[tm][tn];
        a = __builtin_amdgcn_mfma_f32_16x16x32_bf16(ah[tm], b0, a, 0, 0, 0);
        a = __builtin_amdgcn_mfma_f32_16x16x32_bf16(ah[tm], b1, a, 0, 0, 0);
        a = __builtin_amdgcn_mfma_f32_16x16x32_bf16(al[tm], b0, a, 0, 0, 0);
        acc[tm][tn] = a;
      }
    }
  }
  float sum = 0.f, sq = 0.f;
#pragma unroll
  for (int tm = 0; tm < 4; ++tm) {
#pragma unroll
    for (int tn = 0; tn < 4; ++tn) {
#pragma unroll
      for (int r = 0; r < 4; ++r) {
        int m = m0 + wm * 64 + tm * 16 + quad * 4 + r;
        int n = n0 + wn * 64 + tn * 16 + l15;
        size_t idx = (size_t)m * 1024 + n;
        float o = z1[idx] + fmaxf(acc[tm][tn][r] + ffb[n], 0.f);
        s2[idx] = o;
        sum += o; sq += o * o;
      }
    }
  }
  red[tid] = make_float2(sum, sq);
  __syncthreads();
  for (int s = 128; s > 0; s >>= 1) {
    if (tid < s) { red[tid].x += red[tid + s].x; red[tid].y += red[tid + s].y; }
    __syncthreads();
  }
  if (tid == 0) part[blockIdx.x * 8 + blockIdx.y] = red[0];
}

__global__ __launch_bounds__(256) void ln_stats(
    const float2* __restrict__ part, float2* __restrict__ stats, int npart)
{
  __shared__ double sd[256], sq[256];
  const int tid = threadIdx.x;
  float2 p = (tid < npart) ? part[blockIdx.x * npart + tid] : make_float2(0.f, 0.f);
  sd[tid] = (double)p.x; sq[tid] = (double)p.y;
  __syncthreads();
  for (int s = 128; s > 0; s >>= 1) {
    if (tid < s) { sd[tid] += sd[tid + s]; sq[tid] += sq[tid + s]; }
    __syncthreads();
  }
  if (tid == 0) {
    const double n = (double)Tc * Ec;
    double mean = sd[0] / n;
    double var = sq[0] / n - mean * mean;
    if (var < 0.0) var = 0.0;
    double rs = 1.0 / sqrt(var + 1e-5);
    stats[blockIdx.x] = make_float2((float)mean, (float)rs);
  }
}

__global__ __launch_bounds__(256) void ln_norm(
    const float* __restrict__ s, const float2* __restrict__ stats,
    const float* __restrict__ w, const float* __restrict__ bias,
    float* __restrict__ out)
{
  int i = blockIdx.x * 256 + threadIdx.x;
  if (i >= (Bc * Tc * Ec) / 4) return;
  int b = i >> 18;
  int te4 = i & ((1 << 18) - 1);
  float2 st = stats[b];
  float4 sv = ((const float4*)s)[i];
  float4 wv = ((const float4*)w)[te4];
  float4 bv = ((const float4*)bias)[te4];
  float4 o;
  o.x = (sv.x - st.x) * st.y * wv.x + bv.x;
  o.y = (sv.y - st.x) * st.y * wv.y + bv.y;
  o.z = (sv.z - st.x) * st.y * wv.z + bv.z;
  o.w = (sv.w - st.x) * st.y * wv.w + bv.w;
  ((float4*)out)[i] = o;
}

// ---------------------------------------------------------------------------
extern "C" void kernel_launch(void* const* d_in, const int* in_sizes, int n_in,
                              void* d_out, int out_size, void* d_ws, size_t ws_size,
                              hipStream_t stream)
{
  const float* x    = (const float*)d_in[0];
  const float* qw   = (const float*)d_in[1];
  const float* kw   = (const float*)d_in[2];
  const float* vw   = (const float*)d_in[3];
  const float* frw  = (const float*)d_in[4];
  const float* ffw  = (const float*)d_in[5];
  const float* ffb  = (const float*)d_in[6];
  const float* ln1w = (const float*)d_in[7];
  const float* ln1b = (const float*)d_in[8];
  const float* ln2w = (const float*)d_in[9];
  const float* ln2b = (const float*)d_in[10];
  float* out = (float*)d_out;
  char* W = (char*)d_ws;

  const size_t MB = 1ull << 20;
  // Footprint: 56 MB + 16.4 KB (round-4/5 proven).
  // Liveness: qf/kf/vt live proj->attn; wT dead after proj (zb overlays it);
  // frT overlays kf AFTER attn; z1 overlays frT AFTER gemm_fr; s2 overlays
  // vt+zb after gemm_fr.
  float*  qf  = (float*)(W);             // 16 MB fp32 [bh][t][f]
  float*  kf  = (float*)(W + 16 * MB);   // 16 MB fp32 [bh][t][f]
  ushort* vt  = (ushort*)(W + 32 * MB);  //  8 MB bf16 [bh][f][t]
  float*  zb  = (float*)(W + 40 * MB);   // 16 MB fp32 [b][t][e]
  ushort* wT  = (ushort*)(W + 40 * MB);  // 14 MB — dead before attn
  ushort* frT = (ushort*)(W + 16 * MB);  // 16 MB bf16 hi+lo — lives fr only
  float*  s1  = (float*)(W);             // aliases qf
  float*  z1  = (float*)(W + 16 * MB);   // aliases kf/frT
  float*  s2  = (float*)(W + 32 * MB);   // aliases vt+zb
  float2* part1  = (float2*)(W + 56 * MB);
  float2* part2  = part1 + 1024;
  float2* stats1 = part2 + 1024;
  float2* stats2 = stats1 + 4;

  transp_w<<<dim3(16, 16, 3), 256, 0, stream>>>(qw, kw, vw, wT);
  proj_qk_mfma<<<dim3(32, 8, 2), 256, 0, stream>>>(x, wT, qf, kf);
  proj_v_mfma<<<dim3(32, 8), 256, 0, stream>>>(x, wT, vt);
  attn_mfma<<<dim3(16, 64), 256, 0, stream>>>(qf, kf, vt, zb);
  transp_frw<<<dim3(16, 16, 4), 256, 0, stream>>>(frw, frT);
  gemm_fr_mfma<<<dim3(8, 8, 4), 256, 0, stream>>>(zb, frT, x, s1, part1);
  ln_stats<<<dim3(4), 256, 0, stream>>>(part1, stats1, 64);
  ln_norm<<<dim3(4096), 256, 0, stream>>>(s1, stats1, ln1w, ln1b, z1);
  gemm_ff_mfma<<<dim3(32, 8), 256, 0, stream>>>(z1, ffw, ffb, s2, part2);
  ln_stats<<<dim3(4), 256, 0, stream>>>(part2, stats2, 64);
  ln_norm<<<dim3(4096), 256, 0, stream>>>(s2, stats2, ln2w, ln2b, out);
}